// Round 10
// baseline (453.509 us; speedup 1.0000x reference)
//
#include <hip/hip_runtime.h>
#include <hip/hip_fp16.h>
#include <math.h>

typedef __attribute__((ext_vector_type(8))) short    s16x8;   // 8 fp16 (4 VGPRs)
typedef __attribute__((ext_vector_type(8))) _Float16 h16x8;   // MFMA f16 operand
typedef __attribute__((ext_vector_type(4))) float    f32x4;   // MFMA accumulator
typedef __attribute__((ext_vector_type(4))) int      i32x4;

__device__ __forceinline__ short f2h(float x){ return __half_as_short(__float2half(x)); }
__device__ __forceinline__ float h2f(short s){ return __half2float(__short_as_half(s)); }

// ---------------- fused prep: 5 weight transposes + 3 cvec reductions + counts zero ----
__global__ void k_prep(const float* W0, const float* Ws0, const float* W1,
                       const float* Ws1, const float* W2,
                       short* W0t, short* Ws0t, short* W1t, short* Ws1t, short* W2t,
                       const float* Wtp0, const float* a_tp0,
                       const float* Wtp1, const float* a_tp1,
                       const float* Wtp2, const float* a_tp2, float* cvec,
                       int* counts, int N){
  __shared__ float buf[256];
  int b = blockIdx.x;
  if (b < 1024){
    int idx = b*256 + threadIdx.x;           // 0..262143
    const float* W; short* Wt; int K; int base;
    if (idx < 32768)      { W=W0;  Wt=W0t;  K=128; base=0; }
    else if (idx < 65536) { W=Ws0; Wt=Ws0t; K=128; base=32768; }
    else if (idx < 131072){ W=W1;  Wt=W1t;  K=256; base=65536; }
    else if (idx < 196608){ W=Ws1; Wt=Ws1t; K=256; base=131072; }
    else                  { W=W2;  Wt=W2t;  K=256; base=196608; }
    int i = idx - base;
    int n = i / K, k = i - n*K;
    Wt[i] = f2h(W[(size_t)k*256 + n]);
  } else if (b < 1027){
    int layer = b - 1024;
    const float* Wtp = layer==0 ? Wtp0 : (layer==1 ? Wtp1 : Wtp2);
    const float* atp = layer==0 ? a_tp0 : (layer==1 ? a_tp1 : a_tp2);
    float* c = cvec + (layer==0 ? 0 : (layer==1 ? 16 : 32));
    int NH = (layer==2) ? 1 : 16;
    int t = threadIdx.x;
    buf[t] = Wtp[t] * atp[t];
    __syncthreads();
    int F = 256 / NH;
    if (t < NH){
      float s = 0.f;
      for (int f = 0; f < F; f++) s += buf[t*F + f];
      c[t] = s;
    }
  } else {
    int i = (b - 1027)*256 + threadIdx.x;
    if (i < N) counts[i] = 0;
  }
}

// ---------------- CSR build (sort edges by target) ----------------
__global__ void k_hist(const int* tgt, int* counts, int* rank, int E){
  int i = blockIdx.x*blockDim.x + threadIdx.x;
  if (i < E) rank[i] = atomicAdd(&counts[tgt[i]], 1);
}
__global__ void k_scan1(const int* counts, int* row_excl, int* partials, int N){
  __shared__ int buf[1024];
  int t = threadIdx.x; int i = blockIdx.x*1024 + t;
  int v = (i < N) ? counts[i] : 0;
  buf[t] = v; __syncthreads();
  for (int o = 1; o < 1024; o <<= 1){
    int x = (t >= o) ? buf[t-o] : 0;
    __syncthreads();
    buf[t] += x;
    __syncthreads();
  }
  if (i < N) row_excl[i] = buf[t] - v;
  if (t == 1023) partials[blockIdx.x] = buf[1023];
}
__global__ void k_scan3(int* row_start, const int* partials, int N, int E){
  __shared__ int base;
  int b = blockIdx.x;
  int pb = (b*256) >> 10;
  if (threadIdx.x == 0){
    int s = 0;
    for (int k = 0; k < pb; k++) s += partials[k];
    base = s;
  }
  __syncthreads();
  int i = b*256 + threadIdx.x;
  if (i < N) row_start[i] += base;
  if (i == 0) row_start[N] = E;
}
// atomic-free scatter: p = row_start[tgt] + rank; nontemporal 8B store
__global__ void k_scatter(const int* src, const int* tgt, const float* eprob,
                          const int* row_start, const int* rank,
                          long long* es, int E){
  int i = blockIdx.x*blockDim.x + threadIdx.x;
  if (i >= E) return;
  int p = row_start[tgt[i]] + rank[i];
  unsigned long long v = ((unsigned long long)(unsigned)__float_as_int(eprob[i]) << 32)
                       | (unsigned)src[i];
  __builtin_nontemporal_store((long long)v, es + p);
}

// ---------------- LDS-staged MFMA GEMM (fp16/fp32 in, fp16/int8 out) ----------------
// DUAL=1: 512 threads; waves 0-3 compute proj (B1t -> int8 C8 + svec), waves 4-7
//         compute skip (B2t -> fp16 C2b). A staged ONCE, shared via LDS (halves A reads
//         vs the previous y=2 grid).
// DUAL=0: 256 threads; proj only (B1t -> int8 C8 + optional fused NH=1 svec).
// AF32: A operand is fp32 (node features), converted in-register on load.
template<int AF32>
__device__ __forceinline__ s16x8 loadA(const void* Ab, size_t off){
  if constexpr (AF32){
    const float* p = (const float*)Ab + off;
    float4 a0 = *(const float4*)p;
    float4 a1 = *(const float4*)(p + 4);
    s16x8 r;
    r[0]=f2h(a0.x); r[1]=f2h(a0.y); r[2]=f2h(a0.z); r[3]=f2h(a0.w);
    r[4]=f2h(a1.x); r[5]=f2h(a1.y); r[6]=f2h(a1.z); r[7]=f2h(a1.w);
    return r;
  } else {
    return *(const s16x8*)((const short*)Ab + off);
  }
}

template<int KC, int AF32, int DUAL>   // KC: K/32 chunks (4 or 8)
__global__ __launch_bounds__(DUAL ? 512 : 256)
void k_gemm_lds(const void* __restrict__ Ab,
                const short* __restrict__ B1t, const short* __restrict__ B2t,
                short* __restrict__ C2b,
                unsigned char* __restrict__ C8, float* __restrict__ pscale,
                const float* __restrict__ asrc, const float* __restrict__ atgt,
                const float* __restrict__ asrc1, const float* __restrict__ atgt1,
                float* __restrict__ s_src, float* __restrict__ s_tgt, int M){
  const int K = KC*32;
  __shared__ short lA[64*32];                   // 4 KB
  __shared__ short lB[DUAL ? 2 : 1][256*32];    // 16/32 KB
  const int tid  = threadIdx.x;
  const int t8   = tid & 255;      // index within wave-group half
  const int lane = tid & 63;
  const int wave = tid >> 6;
  const int pw   = DUAL ? (wave >> 2) : 0;   // 0 = proj, 1 = skip
  const int cw   = wave & 3;                 // column group (64 cols)
  const int m16  = lane & 15;
  const int q    = lane >> 4;
  const int swz  = (m16 >> 1) & 3;
  const int r0   = blockIdx.x * 64;
  const short* __restrict__ Bt = (DUAL && pw) ? B2t : B1t;

  int arow = r0 + (t8 >> 2); if (arow >= M) arow = M - 1;
  const int akq = (t8 & 3) ^ ((t8 >> 3) & 3);
  int bn[4], bkq[4];
  #pragma unroll
  for (int j = 0; j < 4; j++){
    int sj = j*256 + t8;
    bn[j]  = sj >> 2;
    bkq[j] = (sj & 3) ^ ((sj >> 3) & 3);
  }

  f32x4 acc[4][4];
  #pragma unroll
  for (int mi = 0; mi < 4; mi++)
    #pragma unroll
    for (int ni = 0; ni < 4; ni++) acc[mi][ni] = {0.f,0.f,0.f,0.f};

  s16x8 ra;
  if (!DUAL || pw == 0) ra = loadA<AF32>(Ab, (size_t)arow*K + akq*8);
  s16x8 rb[4];
  #pragma unroll
  for (int j = 0; j < 4; j++)
    rb[j] = *(const s16x8*)(Bt + (size_t)bn[j]*K + bkq[j]*8);

  for (int c = 0; c < KC; c++){
    __syncthreads();
    if (!DUAL || pw == 0) *(s16x8*)(lA + t8*8) = ra;
    #pragma unroll
    for (int j = 0; j < 4; j++)
      *(s16x8*)(lB[pw] + (j*256 + t8)*8) = rb[j];
    __syncthreads();

    if (c + 1 < KC){
      int k0 = (c+1)*32;
      if (!DUAL || pw == 0) ra = loadA<AF32>(Ab, (size_t)arow*K + k0 + akq*8);
      #pragma unroll
      for (int j = 0; j < 4; j++)
        rb[j] = *(const s16x8*)(Bt + (size_t)bn[j]*K + k0 + bkq[j]*8);
    }

    s16x8 Af[4], Bf[4];
    #pragma unroll
    for (int mi = 0; mi < 4; mi++){
      int slot = (mi*16 + m16)*4 + (q ^ swz);
      Af[mi] = *(const s16x8*)(lA + slot*8);
    }
    #pragma unroll
    for (int ni = 0; ni < 4; ni++){
      int n = cw*64 + ni*16 + m16;
      int slot = n*4 + (q ^ swz);
      Bf[ni] = *(const s16x8*)(lB[pw] + slot*8);
    }
    #pragma unroll
    for (int mi = 0; mi < 4; mi++)
      #pragma unroll
      for (int ni = 0; ni < 4; ni++)
        acc[mi][ni] = __builtin_amdgcn_mfma_f32_16x16x32_f16(
            *(h16x8*)&Bf[ni], *(h16x8*)&Af[mi], acc[mi][ni], 0, 0, 0);
  }

  // ---- skip write (fp16), DUAL waves 4-7 ----
  if (DUAL && pw == 1 && C2b){
    #pragma unroll
    for (int mi = 0; mi < 4; mi++){
      int row = r0 + mi*16 + m16;
      if (row < M){
        #pragma unroll
        for (int ni = 0; ni < 4; ni++){
          size_t o = (size_t)row*256 + cw*64 + ni*16 + q*4;
          short4 u; u.x = f2h(acc[mi][ni][0]); u.y = f2h(acc[mi][ni][1]);
          u.z = f2h(acc[mi][ni][2]); u.w = f2h(acc[mi][ni][3]);
          *(short4*)(C2b + o) = u;
        }
      }
    }
  }

  // ---- fused NH=16 svec (proj waves) ----
  if (asrc && (!DUAL || pw == 0)){
    #pragma unroll
    for (int mi = 0; mi < 4; mi++){
      int row = r0 + mi*16 + m16;
      bool ok = (row < M);
      #pragma unroll
      for (int ni = 0; ni < 4; ni++){
        int hh = cw*4 + ni;
        const float* as = asrc + hh*16 + q*4;
        const float* at = atgt + hh*16 + q*4;
        float pss = acc[mi][ni][0]*as[0] + acc[mi][ni][1]*as[1]
                  + acc[mi][ni][2]*as[2] + acc[mi][ni][3]*as[3];
        float pst = acc[mi][ni][0]*at[0] + acc[mi][ni][1]*at[1]
                  + acc[mi][ni][2]*at[2] + acc[mi][ni][3]*at[3];
        pss += __shfl_xor(pss, 16); pss += __shfl_xor(pss, 32);
        pst += __shfl_xor(pst, 16); pst += __shfl_xor(pst, 32);
        if (ok && q == 0){
          s_src[row*16 + hh] = pss;
          s_tgt[row*16 + hh] = pst;
        }
      }
    }
  }

  // ---- fused NH=1 svec (layer 2, DUAL=0): full 256-col dot, cross-wave LDS reduce ----
  if (asrc1){
    float pss[4], pst[4];
    if (!DUAL || pw == 0){
      #pragma unroll
      for (int mi = 0; mi < 4; mi++){
        float ss = 0.f, st = 0.f;
        #pragma unroll
        for (int ni = 0; ni < 4; ni++){
          const float* as = asrc1 + cw*64 + ni*16 + q*4;
          const float* at = atgt1 + cw*64 + ni*16 + q*4;
          #pragma unroll
          for (int k = 0; k < 4; k++){
            ss += acc[mi][ni][k]*as[k];
            st += acc[mi][ni][k]*at[k];
          }
        }
        ss += __shfl_xor(ss, 16); ss += __shfl_xor(ss, 32);
        st += __shfl_xor(st, 16); st += __shfl_xor(st, 32);
        pss[mi] = ss; pst[mi] = st;
      }
    }
    __syncthreads();                       // main-loop LDS reads done
    float* sred = (float*)lB[0];           // [2][4 waves][64 rows] = 2 KB
    if ((!DUAL || pw == 0) && q == 0){
      #pragma unroll
      for (int mi = 0; mi < 4; mi++){
        int r = mi*16 + m16;
        sred[cw*64 + r]       = pss[mi];
        sred[256 + cw*64 + r] = pst[mi];
      }
    }
    __syncthreads();
    if (tid < 64){
      int row = r0 + tid;
      if (row < M){
        float ss = sred[tid] + sred[64+tid] + sred[128+tid] + sred[192+tid];
        float st = sred[256+tid] + sred[320+tid] + sred[384+tid] + sred[448+tid];
        s_src[row] = ss;
        s_tgt[row] = st;
      }
    }
  }

  // ---- per-row-scaled int8 encode (proj waves) ----
  if (C8){
    float am[4];
    if (!DUAL || pw == 0){
      #pragma unroll
      for (int mi = 0; mi < 4; mi++){
        float a = 0.f;
        #pragma unroll
        for (int ni = 0; ni < 4; ni++)
          #pragma unroll
          for (int k = 0; k < 4; k++)
            a = fmaxf(a, fabsf(acc[mi][ni][k]));
        a = fmaxf(a, __shfl_xor(a, 16));
        a = fmaxf(a, __shfl_xor(a, 32));
        am[mi] = a;
      }
    }
    __syncthreads();                      // all waves done with prior LDS use
    float* rmax = (float*)lA;             // [4 col-waves][64 rows] = 1 KB
    if ((!DUAL || pw == 0) && q == 0){
      #pragma unroll
      for (int mi = 0; mi < 4; mi++) rmax[cw*64 + mi*16 + m16] = am[mi];
    }
    __syncthreads();
    if (!DUAL || pw == 0){
      #pragma unroll
      for (int mi = 0; mi < 4; mi++){
        int r = mi*16 + m16;
        int row = r0 + r;
        bool ok = (row < M);
        float s = fmaxf(fmaxf(rmax[r], rmax[64+r]), fmaxf(rmax[128+r], rmax[192+r]));
        float scl = s * (1.f/127.f);
        float inv = (s > 0.f) ? (127.f/s) : 0.f;
        if (ok && cw == 0 && q == 0) pscale[row] = scl;
        if (ok){
          #pragma unroll
          for (int ni = 0; ni < 4; ni++){
            int v0 = __float2int_rn(acc[mi][ni][0]*inv) + 128;
            int v1 = __float2int_rn(acc[mi][ni][1]*inv) + 128;
            int v2 = __float2int_rn(acc[mi][ni][2]*inv) + 128;
            int v3 = __float2int_rn(acc[mi][ni][3]*inv) + 128;
            unsigned pk = (unsigned)(v0 & 255) | ((unsigned)(v1 & 255) << 8)
                        | ((unsigned)(v2 & 255) << 16) | ((unsigned)(v3 & 255) << 24);
            *(unsigned*)(C8 + (size_t)row*256 + cw*64 + ni*16 + q*4) = pk;
          }
        }
      }
    }
  }
}

// ---------------- single-pass fused attention, NH=16 (int8 proj gather) ----------------
template<int LN>
__global__ __launch_bounds__(256)
void k_attn16(const int* __restrict__ row_start, const int2* __restrict__ es,
              const float* __restrict__ s_src, const float* __restrict__ s_tgt,
              const float* __restrict__ cvec,
              const unsigned char* __restrict__ proj8, const float* __restrict__ pscale,
              const short* __restrict__ skipb,
              const float* __restrict__ bias,
              const float* __restrict__ ln_g, const float* __restrict__ ln_b,
              short* __restrict__ houtb, int N){
  __shared__ __align__(16) float wbuf[4][16][20];   // [wave][head][edge(16)+pad]
  __shared__ __align__(16) int   svbuf[4][16];
  __shared__ __align__(16) float scbuf[4][16];
  const int lane = threadIdx.x & 63;
  const int wave = threadIdx.x >> 6;
  const int node = blockIdx.x*4 + wave;
  if (node >= N) return;
  const int beg = row_start[node], end = row_start[node+1];

  const int h2 = lane >> 2;      // head owning this lane's 4 features (aggregation)
  const int j4 = lane & 15;      // edge slot (score phase)
  const int g  = lane >> 4;      // head-quad (score phase)

  const f32x4 stg = *(const f32x4*)(s_tgt + (size_t)node*16 + g*4);
  const f32x4 cg  = *(const f32x4*)(cvec + g*4);

  float d = 0.f, dws = 0.f;
  float acc0 = 0.f, acc1 = 0.f, acc2 = 0.f, acc3 = 0.f;

  for (int s0 = beg; s0 < end; s0 += 16){
    int cnt = end - s0; if (cnt > 16) cnt = 16;
    // ---- Phase A: scores for 16 edges x 16 heads ----
    int i  = s0 + j4;
    bool valid = (i < end);
    int ic = valid ? i : (end - 1);
    int2 e2 = es[ic];
    int sv = e2.x;
    float tp = __int_as_float(e2.y);
    f32x4 rv = *(const f32x4*)(s_src + (size_t)sv*16 + g*4);
    if (g == 0){ svbuf[wave][j4] = sv; scbuf[wave][j4] = pscale[sv]; }
    #pragma unroll
    for (int k = 0; k < 4; k++){
      float e = rv[k] + stg[k] + tp*cg[k];
      e = (e > 0.f) ? e : 0.2f*e;
      wbuf[wave][g*4 + k][j4] = valid ? __expf(e) : 0.f;
    }
    // ---- Phase B: int8 gather + f32 accumulate (pads carry w=0, sv clamped) ----
    const unsigned* __restrict__ pp = (const unsigned*)proj8 + lane;
    for (int j = 0; j < cnt; j += 4){
      f32x4 w4  = *(const f32x4*)&wbuf[wave][h2][j];
      f32x4 sc4 = *(const f32x4*)&scbuf[wave][j];
      i32x4 sv4 = *(const i32x4*)&svbuf[wave][j];
      unsigned q0 = pp[(size_t)sv4.x*64];
      unsigned q1 = pp[(size_t)sv4.y*64];
      unsigned q2 = pp[(size_t)sv4.z*64];
      unsigned q3 = pp[(size_t)sv4.w*64];
      float ws0 = w4.x*sc4.x, ws1 = w4.y*sc4.y, ws2 = w4.z*sc4.z, ws3 = w4.w*sc4.w;
      d   += (w4.x + w4.y) + (w4.z + w4.w);
      dws += (ws0 + ws1) + (ws2 + ws3);
      acc0 += ws0*(float)(q0 & 255) + ws1*(float)(q1 & 255)
            + ws2*(float)(q2 & 255) + ws3*(float)(q3 & 255);
      acc1 += ws0*(float)((q0 >> 8) & 255) + ws1*(float)((q1 >> 8) & 255)
            + ws2*(float)((q2 >> 8) & 255) + ws3*(float)((q3 >> 8) & 255);
      acc2 += ws0*(float)((q0 >> 16) & 255) + ws1*(float)((q1 >> 16) & 255)
            + ws2*(float)((q2 >> 16) & 255) + ws3*(float)((q3 >> 16) & 255);
      acc3 += ws0*(float)(q0 >> 24) + ws1*(float)(q1 >> 24)
            + ws2*(float)(q2 >> 24) + ws3*(float)(q3 >> 24);
    }
  }
  float inv = 1.f / (d + 1e-16f);
  float c128 = 128.f * dws;

  short4 sk = ((const short4*)(skipb + (size_t)node*256))[lane];
  float acc[4];
  acc[0] = (acc0 - c128)*inv + h2f(sk.x); acc[1] = (acc1 - c128)*inv + h2f(sk.y);
  acc[2] = (acc2 - c128)*inv + h2f(sk.z); acc[3] = (acc3 - c128)*inv + h2f(sk.w);

  #pragma unroll
  for (int j = 0; j < 4; j++){
    float v = acc[j] + bias[lane*4 + j];
    acc[j] = (v > 0.f) ? v : (__expf(v) - 1.f);
  }
  if (LN){
    float s  = acc[0] + acc[1] + acc[2] + acc[3];
    float s2 = acc[0]*acc[0] + acc[1]*acc[1] + acc[2]*acc[2] + acc[3]*acc[3];
    for (int o = 32; o > 0; o >>= 1){ s += __shfl_xor(s, o); s2 += __shfl_xor(s2, o); }
    float mu  = s * (1.f/256.f);
    float var = s2 * (1.f/256.f) - mu*mu;
    float rs  = rsqrtf(var + 1e-5f);
    #pragma unroll
    for (int j = 0; j < 4; j++)
      acc[j] = (acc[j] - mu)*rs*ln_g[lane*4 + j] + ln_b[lane*4 + j];
  }
  short4 ub; ub.x = f2h(acc[0]); ub.y = f2h(acc[1]);
  ub.z = f2h(acc[2]); ub.w = f2h(acc[3]);
  ((short4*)(houtb + (size_t)node*256))[lane] = ub;
}

// NH=1 variant (layer 2): int8 message gather; scores from fused GEMM-epilogue svec.
__global__ __launch_bounds__(256)
void k_attn1(const int* __restrict__ row_start, const int2* __restrict__ es,
             const float* __restrict__ s_src, const float* __restrict__ s_tgt,
             const float* __restrict__ cvec,
             const unsigned char* __restrict__ proj8, const float* __restrict__ pscale,
             const short* __restrict__ skipb,
             const float* __restrict__ bias,
             const float* __restrict__ ln_g, const float* __restrict__ ln_b,
             short* __restrict__ houtb, int N){
  __shared__ __align__(16) float wb1[4][64];
  __shared__ __align__(16) int   sb1[4][64];
  __shared__ __align__(16) float scb1[4][64];
  const int lane = threadIdx.x & 63;
  const int wave = threadIdx.x >> 6;
  const int node = blockIdx.x*4 + wave;
  if (node >= N) return;
  const int beg = row_start[node], end = row_start[node+1];

  const float c0 = cvec[0];
  const float st = s_tgt[node];
  float d = 0.f, dws = 0.f;
  float acc0 = 0.f, acc1 = 0.f, acc2 = 0.f, acc3 = 0.f;

  for (int s0 = beg; s0 < end; s0 += 64){
    int cnt = end - s0; if (cnt > 64) cnt = 64;
    // ---- Phase A: one edge per lane ----
    int i  = s0 + lane;
    bool valid = (i < end);
    int ic = valid ? i : (end - 1);
    int2 e2 = es[ic];
    int sv = e2.x;
    float e = s_src[sv] + st + __int_as_float(e2.y)*c0;
    e = (e > 0.f) ? e : 0.2f*e;
    float w = valid ? __expf(e) : 0.f;
    wb1[wave][lane] = w;
    sb1[wave][lane] = sv;
    scb1[wave][lane] = pscale[sv];
    // ---- Phase B: int8 gather + f32 accumulate ----
    const unsigned* __restrict__ pp = (const unsigned*)proj8 + lane;
    for (int j = 0; j < cnt; j += 4){
      f32x4 w4  = *(const f32x4*)&wb1[wave][j];
      f32x4 sc4 = *(const f32x4*)&scb1[wave][j];
      i32x4 sv4 = *(const i32x4*)&sb1[wave][j];
      unsigned q0 = pp[(size_t)sv4.x*64];
      unsigned q1 = pp[(size_t)sv4.y*64];
      unsigned q2 = pp[(size_t)sv4.z*64];
      unsigned q3 = pp[(size_t)sv4.w*64];
      float ws0 = w4.x*sc4.x, ws1 = w4.y*sc4.y, ws2 = w4.z*sc4.z, ws3 = w4.w*sc4.w;
      d   += (w4.x + w4.y) + (w4.z + w4.w);
      dws += (ws0 + ws1) + (ws2 + ws3);
      acc0 += ws0*(float)(q0 & 255) + ws1*(float)(q1 & 255)
            + ws2*(float)(q2 & 255) + ws3*(float)(q3 & 255);
      acc1 += ws0*(float)((q0 >> 8) & 255) + ws1*(float)((q1 >> 8) & 255)
            + ws2*(float)((q2 >> 8) & 255) + ws3*(float)((q3 >> 8) & 255);
      acc2 += ws0*(float)((q0 >> 16) & 255) + ws1*(float)((q1 >> 16) & 255)
            + ws2*(float)((q2 >> 16) & 255) + ws3*(float)((q3 >> 16) & 255);
      acc3 += ws0*(float)(q0 >> 24) + ws1*(float)(q1 >> 24)
            + ws2*(float)(q2 >> 24) + ws3*(float)(q3 >> 24);
    }
  }
  float inv = 1.f / (d + 1e-16f);
  float c128 = 128.f * dws;

  short4 sk = ((const short4*)(skipb + (size_t)node*256))[lane];
  float acc[4];
  acc[0] = (acc0 - c128)*inv + h2f(sk.x); acc[1] = (acc1 - c128)*inv + h2f(sk.y);
  acc[2] = (acc2 - c128)*inv + h2f(sk.z); acc[3] = (acc3 - c128)*inv + h2f(sk.w);

  #pragma unroll
  for (int j = 0; j < 4; j++){
    float v = acc[j] + bias[lane*4 + j];
    acc[j] = (v > 0.f) ? v : (__expf(v) - 1.f);
  }
  float s  = acc[0] + acc[1] + acc[2] + acc[3];
  float s2 = acc[0]*acc[0] + acc[1]*acc[1] + acc[2]*acc[2] + acc[3]*acc[3];
  for (int o = 32; o > 0; o >>= 1){ s += __shfl_xor(s, o); s2 += __shfl_xor(s2, o); }
  float mu  = s * (1.f/256.f);
  float var = s2 * (1.f/256.f) - mu*mu;
  float rs  = rsqrtf(var + 1e-5f);
  #pragma unroll
  for (int j = 0; j < 4; j++)
    acc[j] = (acc[j] - mu)*rs*ln_g[lane*4 + j] + ln_b[lane*4 + j];
  short4 ub; ub.x = f2h(acc[0]); ub.y = f2h(acc[1]);
  ub.z = f2h(acc[2]); ub.w = f2h(acc[3]);
  ((short4*)(houtb + (size_t)node*256))[lane] = ub;
}

// ---------------- final gather (fp16 h -> fp32 out) ----------------
__global__ void k_gather(const short* hb, const int* x, float* out, int R){
  int r = blockIdx.x, t = threadIdx.x;
  if (r >= R) return;
  out[(size_t)r*256 + t] = h2f(hb[(size_t)x[r]*256 + t]);
}

extern "C" void kernel_launch(void* const* d_in, const int* in_sizes, int n_in,
                              void* d_out, int out_size, void* d_ws, size_t ws_size,
                              hipStream_t stream){
  const int N = in_sizes[0] / 128;   // 50000
  const int E = in_sizes[1] / 2;     // 800000
  const int R = in_sizes[3];         // 8192

  const float* nf    = (const float*)d_in[0];
  const int*   ei    = (const int*)d_in[1];
  const float* eprob = (const float*)d_in[2];
  const int*   xidx  = (const int*)d_in[3];
  const float* W0     = (const float*)d_in[4];
  const float* a_src0 = (const float*)d_in[5];
  const float* a_tgt0 = (const float*)d_in[6];
  const float* Wtp0   = (const float*)d_in[7];
  const float* a_tp0  = (const float*)d_in[8];
  const float* Wskip0 = (const float*)d_in[9];
  const float* b0     = (const float*)d_in[10];
  const float* W1     = (const float*)d_in[11];
  const float* a_src1 = (const float*)d_in[12];
  const float* a_tgt1 = (const float*)d_in[13];
  const float* Wtp1   = (const float*)d_in[14];
  const float* a_tp1  = (const float*)d_in[15];
  const float* Wskip1 = (const float*)d_in[16];
  const float* b1     = (const float*)d_in[17];
  const float* ln1_g  = (const float*)d_in[18];
  const float* ln1_b  = (const float*)d_in[19];
  const float* W2     = (const float*)d_in[20];
  const float* a_src2 = (const float*)d_in[21];
  const float* a_tgt2 = (const float*)d_in[22];
  const float* Wtp2   = (const float*)d_in[23];
  const float* a_tp2  = (const float*)d_in[24];
  const float* b2     = (const float*)d_in[25];
  const float* ln2_g  = (const float*)d_in[26];
  const float* ln2_b  = (const float*)d_in[27];

  // ---- workspace layout (~80 MB) ----
  char* ws = (char*)d_ws;
  size_t off = 0;
  auto alloc = [&](size_t bytes)->char*{
    char* p = ws + off; off = (off + bytes + 255) & ~(size_t)255; return p;
  };
  unsigned char* P8 = (unsigned char*)alloc((size_t)N*256);  // proj, int8 (all layers)
  float* pscale    = (float*)alloc((size_t)N*4);       // per-row int8 scale
  short* hXb       = (short*)alloc((size_t)N*256*2);   // fp16 h: L0 out, then L1 out
  short* Skb       = (short*)alloc((size_t)N*256*2);   // skip GEMM out, then final h
  float* s_src     = (float*)alloc((size_t)N*16*4);
  float* s_tgt     = (float*)alloc((size_t)N*16*4);
  float* cvec      = (float*)alloc(256);
  int*   counts    = (int*)alloc((size_t)N*4);
  int*   row_start = (int*)alloc((size_t)(N+1)*4);
  int*   partials  = (int*)alloc(256*4);
  int*   rank      = (int*)alloc((size_t)E*4);         // per-edge rank within tgt
  int2*  es        = (int2*)alloc((size_t)E*8);        // packed (src, tp) sorted by tgt
  short* W0t       = (short*)alloc((size_t)128*256*2);
  short* Ws0t      = (short*)alloc((size_t)128*256*2);
  short* W1t       = (short*)alloc((size_t)256*256*2);
  short* Ws1t      = (short*)alloc((size_t)256*256*2);
  short* W2t       = (short*)alloc((size_t)256*256*2);
  (void)ws_size; (void)n_in; (void)out_size;

  const int* src = ei;
  const int* tgt = ei + E;

  // ---- prep: fused transposes+cvecs+counts-zero ----
  int prep_blocks = 1027 + (N + 255)/256;
  k_prep<<<prep_blocks, 256, 0, stream>>>(W0, Wskip0, W1, Wskip1, W2,
                                          W0t, Ws0t, W1t, Ws1t, W2t,
                                          Wtp0, a_tp0, Wtp1, a_tp1, Wtp2, a_tp2, cvec,
                                          counts, N);

  // ---- CSR build (atomic-free scatter via precomputed ranks) ----
  k_hist<<<(E+255)/256, 256, 0, stream>>>(tgt, counts, rank, E);
  int NB = (N + 1023) / 1024;
  k_scan1<<<NB, 1024, 0, stream>>>(counts, row_start, partials, N);
  k_scan3<<<(N+255)/256, 256, 0, stream>>>(row_start, partials, N, E);
  k_scatter<<<(E+255)/256, 256, 0, stream>>>(src, tgt, eprob, row_start, rank,
                                             (long long*)es, E);

  const int gt = (N + 63) / 64;   // GEMM m-tiles
  const int at = (N + 3) / 4;     // attn blocks (4 waves each)

  // ---- Layer 0: GAT(128 -> 16x16 concat), skip = nf @ Wskip0, ELU, no LN ----
  // Fused proj+skip in one 512-thread block; A (fp32 nf) staged once.
  k_gemm_lds<4,1,1><<<gt, 512, 0, stream>>>(nf, W0t, Ws0t, Skb, P8, pscale,
                                            a_src0, a_tgt0, nullptr, nullptr,
                                            s_src, s_tgt, N);
  k_attn16<0><<<at, 256, 0, stream>>>(row_start, es, s_src, s_tgt, cvec + 0,
                                      P8, pscale, Skb, b0, nullptr, nullptr, hXb, N);

  // ---- Layer 1: GAT(256 -> 16x16 concat), skip = h @ Wskip1, ELU, LN ----
  k_gemm_lds<8,0,1><<<gt, 512, 0, stream>>>(hXb, W1t, Ws1t, Skb, P8, pscale,
                                            a_src1, a_tgt1, nullptr, nullptr,
                                            s_src, s_tgt, N);
  k_attn16<1><<<at, 256, 0, stream>>>(row_start, es, s_src, s_tgt, cvec + 16,
                                      P8, pscale, Skb, b1, ln1_g, ln1_b, hXb, N);

  // ---- Layer 2: GAT(256 -> 1x256, avg = identity), identity skip, ELU, LN ----
  k_gemm_lds<8,0,0><<<gt, 256, 0, stream>>>(hXb, W2t, nullptr, nullptr, P8, pscale,
                                            nullptr, nullptr, a_src2, a_tgt2,
                                            s_src, s_tgt, N);
  k_attn1<<<at, 256, 0, stream>>>(row_start, es, s_src, s_tgt, cvec + 32,
                                  P8, pscale, hXb, b2, ln2_g, ln2_b, Skb, N);

  // ---- gather rows into output (fp32) ----
  k_gather<<<R, 256, 0, stream>>>(Skb, xidx, (float*)d_out, R);
}

// Round 12
// 450.061 us; speedup vs baseline: 1.0077x; 1.0077x over previous
//
#include <hip/hip_runtime.h>
#include <hip/hip_fp16.h>
#include <math.h>

typedef __attribute__((ext_vector_type(8))) short    s16x8;   // 8 fp16 (4 VGPRs)
typedef __attribute__((ext_vector_type(8))) _Float16 h16x8;   // MFMA f16 operand
typedef __attribute__((ext_vector_type(4))) float    f32x4;   // MFMA accumulator
typedef __attribute__((ext_vector_type(4))) int      i32x4;

__device__ __forceinline__ short f2h(float x){ return __half_as_short(__float2half(x)); }
__device__ __forceinline__ float h2f(short s){ return __half2float(__short_as_half(s)); }

// ---------------- fused prep: 5 weight transposes + 3 cvec reductions + counts zero ----
__global__ void k_prep(const float* W0, const float* Ws0, const float* W1,
                       const float* Ws1, const float* W2,
                       short* W0t, short* Ws0t, short* W1t, short* Ws1t, short* W2t,
                       const float* Wtp0, const float* a_tp0,
                       const float* Wtp1, const float* a_tp1,
                       const float* Wtp2, const float* a_tp2, float* cvec,
                       int* counts, int N){
  __shared__ float buf[256];
  int b = blockIdx.x;
  if (b < 1024){
    int idx = b*256 + threadIdx.x;           // 0..262143
    const float* W; short* Wt; int K; int base;
    if (idx < 32768)      { W=W0;  Wt=W0t;  K=128; base=0; }
    else if (idx < 65536) { W=Ws0; Wt=Ws0t; K=128; base=32768; }
    else if (idx < 131072){ W=W1;  Wt=W1t;  K=256; base=65536; }
    else if (idx < 196608){ W=Ws1; Wt=Ws1t; K=256; base=131072; }
    else                  { W=W2;  Wt=W2t;  K=256; base=196608; }
    int i = idx - base;
    int n = i / K, k = i - n*K;
    Wt[i] = f2h(W[(size_t)k*256 + n]);
  } else if (b < 1027){
    int layer = b - 1024;
    const float* Wtp = layer==0 ? Wtp0 : (layer==1 ? Wtp1 : Wtp2);
    const float* atp = layer==0 ? a_tp0 : (layer==1 ? a_tp1 : a_tp2);
    float* c = cvec + (layer==0 ? 0 : (layer==1 ? 16 : 32));
    int NH = (layer==2) ? 1 : 16;
    int t = threadIdx.x;
    buf[t] = Wtp[t] * atp[t];
    __syncthreads();
    int F = 256 / NH;
    if (t < NH){
      float s = 0.f;
      for (int f = 0; f < F; f++) s += buf[t*F + f];
      c[t] = s;
    }
  } else {
    int i = (b - 1027)*256 + threadIdx.x;
    if (i < N) counts[i] = 0;
  }
}

// ---------------- CSR build (sort edges by target) ----------------
__global__ void k_hist(const int* tgt, int* counts, int* rank, int E){
  int i = blockIdx.x*blockDim.x + threadIdx.x;
  if (i < E) rank[i] = atomicAdd(&counts[tgt[i]], 1);
}
__global__ void k_scan1(const int* counts, int* row_excl, int* partials, int N){
  __shared__ int buf[1024];
  int t = threadIdx.x; int i = blockIdx.x*1024 + t;
  int v = (i < N) ? counts[i] : 0;
  buf[t] = v; __syncthreads();
  for (int o = 1; o < 1024; o <<= 1){
    int x = (t >= o) ? buf[t-o] : 0;
    __syncthreads();
    buf[t] += x;
    __syncthreads();
  }
  if (i < N) row_excl[i] = buf[t] - v;
  if (t == 1023) partials[blockIdx.x] = buf[1023];
}
__global__ void k_scan3(int* row_start, const int* partials, int N, int E){
  __shared__ int base;
  int b = blockIdx.x;
  int pb = (b*256) >> 10;
  if (threadIdx.x == 0){
    int s = 0;
    for (int k = 0; k < pb; k++) s += partials[k];
    base = s;
  }
  __syncthreads();
  int i = b*256 + threadIdx.x;
  if (i < N) row_start[i] += base;
  if (i == 0) row_start[N] = E;
}
// atomic-free scatter: p = row_start[tgt] + rank; nontemporal 8B store
__global__ void k_scatter(const int* src, const int* tgt, const float* eprob,
                          const int* row_start, const int* rank,
                          long long* es, int E){
  int i = blockIdx.x*blockDim.x + threadIdx.x;
  if (i >= E) return;
  int p = row_start[tgt[i]] + rank[i];
  unsigned long long v = ((unsigned long long)(unsigned)__float_as_int(eprob[i]) << 32)
                       | (unsigned)src[i];
  __builtin_nontemporal_store((long long)v, es + p);
}

// ---------------- LDS-staged MFMA GEMM (fp16/fp32 in, fp16/int8 out) ----------------
// R9 structure (256-thread independent blocks) + XCD-pairing swizzle:
// PAIRED=1: 1-D grid; tile=(lin>>4)*8+(lin&7), role=(lin>>3)&1 — a tile's proj(role0)
//   and skip(role1) blocks sit 8 apart in linear dispatch order -> same XCD (linear%8
//   round-robin) and near-simultaneous -> the second A-tile read is an L2 hit.
// PAIRED=0: tile=blockIdx.x, role=0 (layer 2: proj only).
// AF32: A operand is fp32 (node features), converted in-register on load.
template<int AF32>
__device__ __forceinline__ s16x8 loadA(const void* Ab, size_t off){
  if constexpr (AF32){
    const float* p = (const float*)Ab + off;
    float4 a0 = *(const float4*)p;
    float4 a1 = *(const float4*)(p + 4);
    s16x8 r;
    r[0]=f2h(a0.x); r[1]=f2h(a0.y); r[2]=f2h(a0.z); r[3]=f2h(a0.w);
    r[4]=f2h(a1.x); r[5]=f2h(a1.y); r[6]=f2h(a1.z); r[7]=f2h(a1.w);
    return r;
  } else {
    return *(const s16x8*)((const short*)Ab + off);
  }
}

template<int KC, int AF32, int PAIRED>   // KC: K/32 chunks (4 or 8)
__global__ __launch_bounds__(256)
void k_gemm_lds(const void* __restrict__ Ab,
                const short* __restrict__ B1t, const short* __restrict__ B2t,
                short* __restrict__ C2b,
                unsigned char* __restrict__ C8, float* __restrict__ pscale,
                const float* __restrict__ asrc, const float* __restrict__ atgt,
                const float* __restrict__ asrc1, const float* __restrict__ atgt1,
                float* __restrict__ s_src, float* __restrict__ s_tgt, int M){
  const int K = KC*32;
  __shared__ short lA[64*32];     // 4 KB
  __shared__ short lB[256*32];    // 16 KB
  const int tid  = threadIdx.x;
  const int lane = tid & 63;
  const int wave = tid >> 6;
  const int m16  = lane & 15;
  const int q    = lane >> 4;
  const int swz  = (m16 >> 1) & 3;

  int tile, role;
  if (PAIRED){
    int lin = blockIdx.x;
    tile = (lin >> 4)*8 + (lin & 7);
    role = (lin >> 3) & 1;
    if (tile >= (M + 63)/64) return;      // block-uniform: no barrier hazard
  } else {
    tile = blockIdx.x; role = 0;
  }
  const int r0 = tile * 64;
  const bool first = (role == 0);
  const short* __restrict__ Bt = first ? B1t : B2t;

  int arow = r0 + (tid >> 2); if (arow >= M) arow = M - 1;
  const int akq = (tid & 3) ^ ((tid >> 3) & 3);
  int bn[4], bkq[4];
  #pragma unroll
  for (int j = 0; j < 4; j++){
    int sj = j*256 + tid;
    bn[j]  = sj >> 2;
    bkq[j] = (sj & 3) ^ ((sj >> 3) & 3);
  }

  f32x4 acc[4][4];
  #pragma unroll
  for (int mi = 0; mi < 4; mi++)
    #pragma unroll
    for (int ni = 0; ni < 4; ni++) acc[mi][ni] = {0.f,0.f,0.f,0.f};

  s16x8 ra = loadA<AF32>(Ab, (size_t)arow*K + akq*8);
  s16x8 rb[4];
  #pragma unroll
  for (int j = 0; j < 4; j++)
    rb[j] = *(const s16x8*)(Bt + (size_t)bn[j]*K + bkq[j]*8);

  for (int c = 0; c < KC; c++){
    __syncthreads();
    *(s16x8*)(lA + tid*8) = ra;
    #pragma unroll
    for (int j = 0; j < 4; j++)
      *(s16x8*)(lB + (j*256 + tid)*8) = rb[j];
    __syncthreads();

    if (c + 1 < KC){
      int k0 = (c+1)*32;
      ra = loadA<AF32>(Ab, (size_t)arow*K + k0 + akq*8);
      #pragma unroll
      for (int j = 0; j < 4; j++)
        rb[j] = *(const s16x8*)(Bt + (size_t)bn[j]*K + k0 + bkq[j]*8);
    }

    s16x8 Af[4], Bf[4];
    #pragma unroll
    for (int mi = 0; mi < 4; mi++){
      int slot = (mi*16 + m16)*4 + (q ^ swz);
      Af[mi] = *(const s16x8*)(lA + slot*8);
    }
    #pragma unroll
    for (int ni = 0; ni < 4; ni++){
      int n = wave*64 + ni*16 + m16;
      int slot = n*4 + (q ^ swz);
      Bf[ni] = *(const s16x8*)(lB + slot*8);
    }
    #pragma unroll
    for (int mi = 0; mi < 4; mi++)
      #pragma unroll
      for (int ni = 0; ni < 4; ni++)
        acc[mi][ni] = __builtin_amdgcn_mfma_f32_16x16x32_f16(
            *(h16x8*)&Bf[ni], *(h16x8*)&Af[mi], acc[mi][ni], 0, 0, 0);
  }

  // ---- skip write (fp16), role 1 ----
  if (!first && C2b){
    #pragma unroll
    for (int mi = 0; mi < 4; mi++){
      int row = r0 + mi*16 + m16;
      if (row < M){
        #pragma unroll
        for (int ni = 0; ni < 4; ni++){
          size_t o = (size_t)row*256 + wave*64 + ni*16 + q*4;
          short4 u; u.x = f2h(acc[mi][ni][0]); u.y = f2h(acc[mi][ni][1]);
          u.z = f2h(acc[mi][ni][2]); u.w = f2h(acc[mi][ni][3]);
          *(short4*)(C2b + o) = u;
        }
      }
    }
  }

  // ---- fused NH=16 svec (role 0) ----
  if (first && asrc){
    #pragma unroll
    for (int mi = 0; mi < 4; mi++){
      int row = r0 + mi*16 + m16;
      bool ok = (row < M);
      #pragma unroll
      for (int ni = 0; ni < 4; ni++){
        int hh = wave*4 + ni;
        const float* as = asrc + hh*16 + q*4;
        const float* at = atgt + hh*16 + q*4;
        float pss = acc[mi][ni][0]*as[0] + acc[mi][ni][1]*as[1]
                  + acc[mi][ni][2]*as[2] + acc[mi][ni][3]*as[3];
        float pst = acc[mi][ni][0]*at[0] + acc[mi][ni][1]*at[1]
                  + acc[mi][ni][2]*at[2] + acc[mi][ni][3]*at[3];
        pss += __shfl_xor(pss, 16); pss += __shfl_xor(pss, 32);
        pst += __shfl_xor(pst, 16); pst += __shfl_xor(pst, 32);
        if (ok && q == 0){
          s_src[row*16 + hh] = pss;
          s_tgt[row*16 + hh] = pst;
        }
      }
    }
  }

  // ---- fused NH=1 svec (layer 2): full 256-col dot per row, cross-wave LDS reduce ----
  if (first && asrc1){
    float pss[4], pst[4];
    #pragma unroll
    for (int mi = 0; mi < 4; mi++){
      float ss = 0.f, st = 0.f;
      #pragma unroll
      for (int ni = 0; ni < 4; ni++){
        const float* as = asrc1 + wave*64 + ni*16 + q*4;
        const float* at = atgt1 + wave*64 + ni*16 + q*4;
        #pragma unroll
        for (int k = 0; k < 4; k++){
          ss += acc[mi][ni][k]*as[k];
          st += acc[mi][ni][k]*at[k];
        }
      }
      ss += __shfl_xor(ss, 16); ss += __shfl_xor(ss, 32);
      st += __shfl_xor(st, 16); st += __shfl_xor(st, 32);
      pss[mi] = ss; pst[mi] = st;
    }
    __syncthreads();                       // main-loop lB reads done
    float* sred = (float*)lB;              // [2][4 waves][64 rows] = 2 KB
    if (q == 0){
      #pragma unroll
      for (int mi = 0; mi < 4; mi++){
        int r = mi*16 + m16;
        sred[wave*64 + r]       = pss[mi];
        sred[256 + wave*64 + r] = pst[mi];
      }
    }
    __syncthreads();
    if (tid < 64){
      int row = r0 + tid;
      if (row < M){
        float ss = sred[tid] + sred[64+tid] + sred[128+tid] + sred[192+tid];
        float st = sred[256+tid] + sred[320+tid] + sred[384+tid] + sred[448+tid];
        s_src[row] = ss;
        s_tgt[row] = st;
      }
    }
  }

  // ---- per-row-scaled int8 encode (role 0) ----
  if (first && C8){
    float am[4];
    #pragma unroll
    for (int mi = 0; mi < 4; mi++){
      float a = 0.f;
      #pragma unroll
      for (int ni = 0; ni < 4; ni++)
        #pragma unroll
        for (int k = 0; k < 4; k++)
          a = fmaxf(a, fabsf(acc[mi][ni][k]));
      a = fmaxf(a, __shfl_xor(a, 16));
      a = fmaxf(a, __shfl_xor(a, 32));
      am[mi] = a;
    }
    __syncthreads();                      // all waves done with prior LDS use
    float* rmax = (float*)lA;             // [wave][64 rows] = 1 KB, reuse lA
    if (q == 0){
      #pragma unroll
      for (int mi = 0; mi < 4; mi++) rmax[wave*64 + mi*16 + m16] = am[mi];
    }
    __syncthreads();
    #pragma unroll
    for (int mi = 0; mi < 4; mi++){
      int r = mi*16 + m16;
      int row = r0 + r;
      bool ok = (row < M);
      float s = fmaxf(fmaxf(rmax[r], rmax[64+r]), fmaxf(rmax[128+r], rmax[192+r]));
      float scl = s * (1.f/127.f);
      float inv = (s > 0.f) ? (127.f/s) : 0.f;
      if (ok && wave == 0 && q == 0) pscale[row] = scl;
      if (ok){
        #pragma unroll
        for (int ni = 0; ni < 4; ni++){
          int v0 = __float2int_rn(acc[mi][ni][0]*inv) + 128;
          int v1 = __float2int_rn(acc[mi][ni][1]*inv) + 128;
          int v2 = __float2int_rn(acc[mi][ni][2]*inv) + 128;
          int v3 = __float2int_rn(acc[mi][ni][3]*inv) + 128;
          unsigned pk = (unsigned)(v0 & 255) | ((unsigned)(v1 & 255) << 8)
                      | ((unsigned)(v2 & 255) << 16) | ((unsigned)(v3 & 255) << 24);
          *(unsigned*)(C8 + (size_t)row*256 + wave*64 + ni*16 + q*4) = pk;
        }
      }
    }
  }
}

// ---------------- single-pass fused attention, NH=16 (int8 proj gather) ----------------
template<int LN>
__global__ __launch_bounds__(256)
void k_attn16(const int* __restrict__ row_start, const int2* __restrict__ es,
              const float* __restrict__ s_src, const float* __restrict__ s_tgt,
              const float* __restrict__ cvec,
              const unsigned char* __restrict__ proj8, const float* __restrict__ pscale,
              const short* __restrict__ skipb,
              const float* __restrict__ bias,
              const float* __restrict__ ln_g, const float* __restrict__ ln_b,
              short* __restrict__ houtb, int N){
  __shared__ __align__(16) float wbuf[4][16][20];   // [wave][head][edge(16)+pad]
  __shared__ __align__(16) int   svbuf[4][16];
  __shared__ __align__(16) float scbuf[4][16];
  const int lane = threadIdx.x & 63;
  const int wave = threadIdx.x >> 6;
  const int node = blockIdx.x*4 + wave;
  if (node >= N) return;
  const int beg = row_start[node], end = row_start[node+1];

  const int h2 = lane >> 2;      // head owning this lane's 4 features (aggregation)
  const int j4 = lane & 15;      // edge slot (score phase)
  const int g  = lane >> 4;      // head-quad (score phase)

  const f32x4 stg = *(const f32x4*)(s_tgt + (size_t)node*16 + g*4);
  const f32x4 cg  = *(const f32x4*)(cvec + g*4);

  float d = 0.f, dws = 0.f;
  float acc0 = 0.f, acc1 = 0.f, acc2 = 0.f, acc3 = 0.f;

  for (int s0 = beg; s0 < end; s0 += 16){
    int cnt = end - s0; if (cnt > 16) cnt = 16;
    // ---- Phase A: scores for 16 edges x 16 heads ----
    int i  = s0 + j4;
    bool valid = (i < end);
    int ic = valid ? i : (end - 1);
    int2 e2 = es[ic];
    int sv = e2.x;
    float tp = __int_as_float(e2.y);
    f32x4 rv = *(const f32x4*)(s_src + (size_t)sv*16 + g*4);
    if (g == 0){ svbuf[wave][j4] = sv; scbuf[wave][j4] = pscale[sv]; }
    #pragma unroll
    for (int k = 0; k < 4; k++){
      float e = rv[k] + stg[k] + tp*cg[k];
      e = (e > 0.f) ? e : 0.2f*e;
      wbuf[wave][g*4 + k][j4] = valid ? __expf(e) : 0.f;
    }
    // ---- Phase B: int8 gather + f32 accumulate (pads carry w=0, sv clamped) ----
    const unsigned* __restrict__ pp = (const unsigned*)proj8 + lane;
    for (int j = 0; j < cnt; j += 4){
      f32x4 w4  = *(const f32x4*)&wbuf[wave][h2][j];
      f32x4 sc4 = *(const f32x4*)&scbuf[wave][j];
      i32x4 sv4 = *(const i32x4*)&svbuf[wave][j];
      unsigned q0 = pp[(size_t)sv4.x*64];
      unsigned q1 = pp[(size_t)sv4.y*64];
      unsigned q2 = pp[(size_t)sv4.z*64];
      unsigned q3 = pp[(size_t)sv4.w*64];
      float ws0 = w4.x*sc4.x, ws1 = w4.y*sc4.y, ws2 = w4.z*sc4.z, ws3 = w4.w*sc4.w;
      d   += (w4.x + w4.y) + (w4.z + w4.w);
      dws += (ws0 + ws1) + (ws2 + ws3);
      acc0 += ws0*(float)(q0 & 255) + ws1*(float)(q1 & 255)
            + ws2*(float)(q2 & 255) + ws3*(float)(q3 & 255);
      acc1 += ws0*(float)((q0 >> 8) & 255) + ws1*(float)((q1 >> 8) & 255)
            + ws2*(float)((q2 >> 8) & 255) + ws3*(float)((q3 >> 8) & 255);
      acc2 += ws0*(float)((q0 >> 16) & 255) + ws1*(float)((q1 >> 16) & 255)
            + ws2*(float)((q2 >> 16) & 255) + ws3*(float)((q3 >> 16) & 255);
      acc3 += ws0*(float)(q0 >> 24) + ws1*(float)(q1 >> 24)
            + ws2*(float)(q2 >> 24) + ws3*(float)(q3 >> 24);
    }
  }
  float inv = 1.f / (d + 1e-16f);
  float c128 = 128.f * dws;

  short4 sk = ((const short4*)(skipb + (size_t)node*256))[lane];
  float acc[4];
  acc[0] = (acc0 - c128)*inv + h2f(sk.x); acc[1] = (acc1 - c128)*inv + h2f(sk.y);
  acc[2] = (acc2 - c128)*inv + h2f(sk.z); acc[3] = (acc3 - c128)*inv + h2f(sk.w);

  #pragma unroll
  for (int j = 0; j < 4; j++){
    float v = acc[j] + bias[lane*4 + j];
    acc[j] = (v > 0.f) ? v : (__expf(v) - 1.f);
  }
  if (LN){
    float s  = acc[0] + acc[1] + acc[2] + acc[3];
    float s2 = acc[0]*acc[0] + acc[1]*acc[1] + acc[2]*acc[2] + acc[3]*acc[3];
    for (int o = 32; o > 0; o >>= 1){ s += __shfl_xor(s, o); s2 += __shfl_xor(s2, o); }
    float mu  = s * (1.f/256.f);
    float var = s2 * (1.f/256.f) - mu*mu;
    float rs  = rsqrtf(var + 1e-5f);
    #pragma unroll
    for (int j = 0; j < 4; j++)
      acc[j] = (acc[j] - mu)*rs*ln_g[lane*4 + j] + ln_b[lane*4 + j];
  }
  short4 ub; ub.x = f2h(acc[0]); ub.y = f2h(acc[1]);
  ub.z = f2h(acc[2]); ub.w = f2h(acc[3]);
  ((short4*)(houtb + (size_t)node*256))[lane] = ub;
}

// NH=1 variant (layer 2): int8 message gather; scores from fused GEMM-epilogue svec.
__global__ __launch_bounds__(256)
void k_attn1(const int* __restrict__ row_start, const int2* __restrict__ es,
             const float* __restrict__ s_src, const float* __restrict__ s_tgt,
             const float* __restrict__ cvec,
             const unsigned char* __restrict__ proj8, const float* __restrict__ pscale,
             const short* __restrict__ skipb,
             const float* __restrict__ bias,
             const float* __restrict__ ln_g, const float* __restrict__ ln_b,
             short* __restrict__ houtb, int N){
  __shared__ __align__(16) float wb1[4][64];
  __shared__ __align__(16) int   sb1[4][64];
  __shared__ __align__(16) float scb1[4][64];
  const int lane = threadIdx.x & 63;
  const int wave = threadIdx.x >> 6;
  const int node = blockIdx.x*4 + wave;
  if (node >= N) return;
  const int beg = row_start[node], end = row_start[node+1];

  const float c0 = cvec[0];
  const float st = s_tgt[node];
  float d = 0.f, dws = 0.f;
  float acc0 = 0.f, acc1 = 0.f, acc2 = 0.f, acc3 = 0.f;

  for (int s0 = beg; s0 < end; s0 += 64){
    int cnt = end - s0; if (cnt > 64) cnt = 64;
    // ---- Phase A: one edge per lane ----
    int i  = s0 + lane;
    bool valid = (i < end);
    int ic = valid ? i : (end - 1);
    int2 e2 = es[ic];
    int sv = e2.x;
    float e = s_src[sv] + st + __int_as_float(e2.y)*c0;
    e = (e > 0.f) ? e : 0.2f*e;
    float w = valid ? __expf(e) : 0.f;
    wb1[wave][lane] = w;
    sb1[wave][lane] = sv;
    scb1[wave][lane] = pscale[sv];
    // ---- Phase B: int8 gather + f32 accumulate ----
    const unsigned* __restrict__ pp = (const unsigned*)proj8 + lane;
    for (int j = 0; j < cnt; j += 4){
      f32x4 w4  = *(const f32x4*)&wb1[wave][j];
      f32x4 sc4 = *(const f32x4*)&scb1[wave][j];
      i32x4 sv4 = *(const i32x4*)&sb1[wave][j];
      unsigned q0 = pp[(size_t)sv4.x*64];
      unsigned q1 = pp[(size_t)sv4.y*64];
      unsigned q2 = pp[(size_t)sv4.z*64];
      unsigned q3 = pp[(size_t)sv4.w*64];
      float ws0 = w4.x*sc4.x, ws1 = w4.y*sc4.y, ws2 = w4.z*sc4.z, ws3 = w4.w*sc4.w;
      d   += (w4.x + w4.y) + (w4.z + w4.w);
      dws += (ws0 + ws1) + (ws2 + ws3);
      acc0 += ws0*(float)(q0 & 255) + ws1*(float)(q1 & 255)
            + ws2*(float)(q2 & 255) + ws3*(float)(q3 & 255);
      acc1 += ws0*(float)((q0 >> 8) & 255) + ws1*(float)((q1 >> 8) & 255)
            + ws2*(float)((q2 >> 8) & 255) + ws3*(float)((q3 >> 8) & 255);
      acc2 += ws0*(float)((q0 >> 16) & 255) + ws1*(float)((q1 >> 16) & 255)
            + ws2*(float)((q2 >> 16) & 255) + ws3*(float)((q3 >> 16) & 255);
      acc3 += ws0*(float)(q0 >> 24) + ws1*(float)(q1 >> 24)
            + ws2*(float)(q2 >> 24) + ws3*(float)(q3 >> 24);
    }
  }
  float inv = 1.f / (d + 1e-16f);
  float c128 = 128.f * dws;

  short4 sk = ((const short4*)(skipb + (size_t)node*256))[lane];
  float acc[4];
  acc[0] = (acc0 - c128)*inv + h2f(sk.x); acc[1] = (acc1 - c128)*inv + h2f(sk.y);
  acc[2] = (acc2 - c128)*inv + h2f(sk.z); acc[3] = (acc3 - c128)*inv + h2f(sk.w);

  #pragma unroll
  for (int j = 0; j < 4; j++){
    float v = acc[j] + bias[lane*4 + j];
    acc[j] = (v > 0.f) ? v : (__expf(v) - 1.f);
  }
  float s  = acc[0] + acc[1] + acc[2] + acc[3];
  float s2 = acc[0]*acc[0] + acc[1]*acc[1] + acc[2]*acc[2] + acc[3]*acc[3];
  for (int o = 32; o > 0; o >>= 1){ s += __shfl_xor(s, o); s2 += __shfl_xor(s2, o); }
  float mu  = s * (1.f/256.f);
  float var = s2 * (1.f/256.f) - mu*mu;
  float rs  = rsqrtf(var + 1e-5f);
  #pragma unroll
  for (int j = 0; j < 4; j++)
    acc[j] = (acc[j] - mu)*rs*ln_g[lane*4 + j] + ln_b[lane*4 + j];
  short4 ub; ub.x = f2h(acc[0]); ub.y = f2h(acc[1]);
  ub.z = f2h(acc[2]); ub.w = f2h(acc[3]);
  ((short4*)(houtb + (size_t)node*256))[lane] = ub;
}

// ---------------- final gather (fp16 h -> fp32 out) ----------------
__global__ void k_gather(const short* hb, const int* x, float* out, int R){
  int r = blockIdx.x, t = threadIdx.x;
  if (r >= R) return;
  out[(size_t)r*256 + t] = h2f(hb[(size_t)x[r]*256 + t]);
}

extern "C" void kernel_launch(void* const* d_in, const int* in_sizes, int n_in,
                              void* d_out, int out_size, void* d_ws, size_t ws_size,
                              hipStream_t stream){
  const int N = in_sizes[0] / 128;   // 50000
  const int E = in_sizes[1] / 2;     // 800000
  const int R = in_sizes[3];         // 8192

  const float* nf    = (const float*)d_in[0];
  const int*   ei    = (const int*)d_in[1];
  const float* eprob = (const float*)d_in[2];
  const int*   xidx  = (const int*)d_in[3];
  const float* W0     = (const float*)d_in[4];
  const float* a_src0 = (const float*)d_in[5];
  const float* a_tgt0 = (const float*)d_in[6];
  const float* Wtp0   = (const float*)d_in[7];
  const float* a_tp0  = (const float*)d_in[8];
  const float* Wskip0 = (const float*)d_in[9];
  const float* b0     = (const float*)d_in[10];
  const float* W1     = (const float*)d_in[11];
  const float* a_src1 = (const float*)d_in[12];
  const float* a_tgt1 = (const float*)d_in[13];
  const float* Wtp1   = (const float*)d_in[14];
  const float* a_tp1  = (const float*)d_in[15];
  const float* Wskip1 = (const float*)d_in[16];
  const float* b1     = (const float*)d_in[17];
  const float* ln1_g  = (const float*)d_in[18];
  const float* ln1_b  = (const float*)d_in[19];
  const float* W2     = (const float*)d_in[20];
  const float* a_src2 = (const float*)d_in[21];
  const float* a_tgt2 = (const float*)d_in[22];
  const float* Wtp2   = (const float*)d_in[23];
  const float* a_tp2  = (const float*)d_in[24];
  const float* b2     = (const float*)d_in[25];
  const float* ln2_g  = (const float*)d_in[26];
  const float* ln2_b  = (const float*)d_in[27];

  // ---- workspace layout (~80 MB) ----
  char* ws = (char*)d_ws;
  size_t off = 0;
  auto alloc = [&](size_t bytes)->char*{
    char* p = ws + off; off = (off + bytes + 255) & ~(size_t)255; return p;
  };
  unsigned char* P8 = (unsigned char*)alloc((size_t)N*256);  // proj, int8 (all layers)
  float* pscale    = (float*)alloc((size_t)N*4);       // per-row int8 scale
  short* hXb       = (short*)alloc((size_t)N*256*2);   // fp16 h: L0 out, then L1 out
  short* Skb       = (short*)alloc((size_t)N*256*2);   // skip GEMM out, then final h
  float* s_src     = (float*)alloc((size_t)N*16*4);
  float* s_tgt     = (float*)alloc((size_t)N*16*4);
  float* cvec      = (float*)alloc(256);
  int*   counts    = (int*)alloc((size_t)N*4);
  int*   row_start = (int*)alloc((size_t)(N+1)*4);
  int*   partials  = (int*)alloc(256*4);
  int*   rank      = (int*)alloc((size_t)E*4);         // per-edge rank within tgt
  int2*  es        = (int2*)alloc((size_t)E*8);        // packed (src, tp) sorted by tgt
  short* W0t       = (short*)alloc((size_t)128*256*2);
  short* Ws0t      = (short*)alloc((size_t)128*256*2);
  short* W1t       = (short*)alloc((size_t)256*256*2);
  short* Ws1t      = (short*)alloc((size_t)256*256*2);
  short* W2t       = (short*)alloc((size_t)256*256*2);
  (void)ws_size; (void)n_in; (void)out_size;

  const int* src = ei;
  const int* tgt = ei + E;

  // ---- prep: fused transposes+cvecs+counts-zero ----
  int prep_blocks = 1027 + (N + 255)/256;
  k_prep<<<prep_blocks, 256, 0, stream>>>(W0, Wskip0, W1, Wskip1, W2,
                                          W0t, Ws0t, W1t, Ws1t, W2t,
                                          Wtp0, a_tp0, Wtp1, a_tp1, Wtp2, a_tp2, cvec,
                                          counts, N);

  // ---- CSR build (atomic-free scatter via precomputed ranks) ----
  k_hist<<<(E+255)/256, 256, 0, stream>>>(tgt, counts, rank, E);
  int NB = (N + 1023) / 1024;
  k_scan1<<<NB, 1024, 0, stream>>>(counts, row_start, partials, N);
  k_scan3<<<(N+255)/256, 256, 0, stream>>>(row_start, partials, N, E);
  k_scatter<<<(E+255)/256, 256, 0, stream>>>(src, tgt, eprob, row_start, rank,
                                             (long long*)es, E);

  const int gt = (N + 63) / 64;           // GEMM m-tiles
  const int gp = ((gt + 7) / 8) * 16;     // paired-swizzle grid (proj+skip co-XCD)
  const int at = (N + 3) / 4;             // attn blocks (4 waves each)

  // ---- Layer 0: GAT(128 -> 16x16 concat), skip = nf @ Wskip0, ELU, no LN ----
  k_gemm_lds<4,1,1><<<gp, 256, 0, stream>>>(nf, W0t, Ws0t, Skb, P8, pscale,
                                            a_src0, a_tgt0, nullptr, nullptr,
                                            s_src, s_tgt, N);
  k_attn16<0><<<at, 256, 0, stream>>>(row_start, es, s_src, s_tgt, cvec + 0,
                                      P8, pscale, Skb, b0, nullptr, nullptr, hXb, N);

  // ---- Layer 1: GAT(256 -> 16x16 concat), skip = h @ Wskip1, ELU, LN ----
  k_gemm_lds<8,0,1><<<gp, 256, 0, stream>>>(hXb, W1t, Ws1t, Skb, P8, pscale,
                                            a_src1, a_tgt1, nullptr, nullptr,
                                            s_src, s_tgt, N);
  k_attn16<1><<<at, 256, 0, stream>>>(row_start, es, s_src, s_tgt, cvec + 16,
                                      P8, pscale, Skb, b1, ln1_g, ln1_b, hXb, N);

  // ---- Layer 2: GAT(256 -> 1x256, avg = identity), identity skip, ELU, LN ----
  k_gemm_lds<8,0,0><<<gt, 256, 0, stream>>>(hXb, W2t, nullptr, nullptr, P8, pscale,
                                            nullptr, nullptr, a_src2, a_tgt2,
                                            s_src, s_tgt, N);
  k_attn1<<<at, 256, 0, stream>>>(row_start, es, s_src, s_tgt, cvec + 32,
                                  P8, pscale, hXb, b2, ln2_g, ln2_b, Skb, N);

  // ---- gather rows into output (fp32) ----
  k_gather<<<R, 256, 0, stream>>>(Skb, xidx, (float*)d_out, R);
}

// Round 13
// 440.406 us; speedup vs baseline: 1.0298x; 1.0219x over previous
//
#include <hip/hip_runtime.h>
#include <hip/hip_fp16.h>
#include <math.h>

typedef __attribute__((ext_vector_type(8))) short    s16x8;   // 8 fp16 (4 VGPRs)
typedef __attribute__((ext_vector_type(8))) _Float16 h16x8;   // MFMA f16 operand
typedef __attribute__((ext_vector_type(4))) float    f32x4;   // MFMA accumulator
typedef __attribute__((ext_vector_type(4))) int      i32x4;

__device__ __forceinline__ short f2h(float x){ return __half_as_short(__float2half(x)); }
__device__ __forceinline__ float h2f(short s){ return __half2float(__short_as_half(s)); }

// ---------------- fused prep: 5 weight transposes + 3 cvec reductions + counts zero ----
__global__ void k_prep(const float* W0, const float* Ws0, const float* W1,
                       const float* Ws1, const float* W2,
                       short* W0t, short* Ws0t, short* W1t, short* Ws1t, short* W2t,
                       const float* Wtp0, const float* a_tp0,
                       const float* Wtp1, const float* a_tp1,
                       const float* Wtp2, const float* a_tp2, float* cvec,
                       int* counts, int N){
  __shared__ float buf[256];
  int b = blockIdx.x;
  if (b < 1024){
    int idx = b*256 + threadIdx.x;           // 0..262143
    const float* W; short* Wt; int K; int base;
    if (idx < 32768)      { W=W0;  Wt=W0t;  K=128; base=0; }
    else if (idx < 65536) { W=Ws0; Wt=Ws0t; K=128; base=32768; }
    else if (idx < 131072){ W=W1;  Wt=W1t;  K=256; base=65536; }
    else if (idx < 196608){ W=Ws1; Wt=Ws1t; K=256; base=131072; }
    else                  { W=W2;  Wt=W2t;  K=256; base=196608; }
    int i = idx - base;
    int n = i / K, k = i - n*K;
    Wt[i] = f2h(W[(size_t)k*256 + n]);
  } else if (b < 1027){
    int layer = b - 1024;
    const float* Wtp = layer==0 ? Wtp0 : (layer==1 ? Wtp1 : Wtp2);
    const float* atp = layer==0 ? a_tp0 : (layer==1 ? a_tp1 : a_tp2);
    float* c = cvec + (layer==0 ? 0 : (layer==1 ? 16 : 32));
    int NH = (layer==2) ? 1 : 16;
    int t = threadIdx.x;
    buf[t] = Wtp[t] * atp[t];
    __syncthreads();
    int F = 256 / NH;
    if (t < NH){
      float s = 0.f;
      for (int f = 0; f < F; f++) s += buf[t*F + f];
      c[t] = s;
    }
  } else {
    int i = (b - 1027)*256 + threadIdx.x;
    if (i < N) counts[i] = 0;
  }
}

// ---------------- CSR build (sort edges by target) ----------------
// hist + per-edge rank (rank = position among same-tgt edges in list order)
__global__ void k_hist(const int* tgt, int* counts, int* rank, int E){
  int i = blockIdx.x*blockDim.x + threadIdx.x;
  if (i < E) rank[i] = atomicAdd(&counts[tgt[i]], 1);
}
__global__ void k_scan1(const int* counts, int* row_excl, int* partials, int N){
  __shared__ int buf[1024];
  int t = threadIdx.x; int i = blockIdx.x*1024 + t;
  int v = (i < N) ? counts[i] : 0;
  buf[t] = v; __syncthreads();
  for (int o = 1; o < 1024; o <<= 1){
    int x = (t >= o) ? buf[t-o] : 0;
    __syncthreads();
    buf[t] += x;
    __syncthreads();
  }
  if (i < N) row_excl[i] = buf[t] - v;
  if (t == 1023) partials[blockIdx.x] = buf[1023];
}
// adds global prefix of partials (computed in-block, NB<=64) and finalizes row_start
__global__ void k_scan3(int* row_start, const int* partials, int N, int E){
  __shared__ int base;
  int b = blockIdx.x;
  int pb = (b*256) >> 10;
  if (threadIdx.x == 0){
    int s = 0;
    for (int k = 0; k < pb; k++) s += partials[k];
    base = s;
  }
  __syncthreads();
  int i = b*256 + threadIdx.x;
  if (i < N) row_start[i] += base;
  if (i == 0) row_start[N] = E;
}
// atomic-free scatter: p = row_start[tgt] + rank; nontemporal 8B store (bypass L2 —
// partial-line writes go to fabric with byte enables instead of 8x line amplification)
__global__ void k_scatter(const int* src, const int* tgt, const float* eprob,
                          const int* row_start, const int* rank,
                          long long* es, int E){
  int i = blockIdx.x*blockDim.x + threadIdx.x;
  if (i >= E) return;
  int p = row_start[tgt[i]] + rank[i];
  unsigned long long v = ((unsigned long long)(unsigned)__float_as_int(eprob[i]) << 32)
                       | (unsigned)src[i];
  __builtin_nontemporal_store((long long)v, es + p);
}

// ---------------- LDS-staged MFMA GEMM (fp16/fp32 in, fp16/int8 out) ----------------
// AF32: A operand is fp32 (node features) — converted in-register on load.
// y=0: proj -> int8 C8+pscale (if non-null), fused NH=16 svec (asrc/atgt) or fused
//      NH=1 svec (asrc1/atgt1, full-row dot via LDS reduce).
// y=1: skip -> fp16 C2b.
template<int AF32>
__device__ __forceinline__ s16x8 loadA(const void* Ab, size_t off){
  if constexpr (AF32){
    const float* p = (const float*)Ab + off;
    float4 a0 = *(const float4*)p;
    float4 a1 = *(const float4*)(p + 4);
    s16x8 r;
    r[0]=f2h(a0.x); r[1]=f2h(a0.y); r[2]=f2h(a0.z); r[3]=f2h(a0.w);
    r[4]=f2h(a1.x); r[5]=f2h(a1.y); r[6]=f2h(a1.z); r[7]=f2h(a1.w);
    return r;
  } else {
    return *(const s16x8*)((const short*)Ab + off);
  }
}

template<int KC, int AF32>   // K/32 chunks: 4 (K=128) or 8 (K=256)
__global__ __launch_bounds__(256)
void k_gemm_lds(const void* __restrict__ Ab,
                const short* __restrict__ B1t, const short* __restrict__ B2t,
                short* __restrict__ C2b,
                unsigned char* __restrict__ C8, float* __restrict__ pscale,
                const float* __restrict__ asrc, const float* __restrict__ atgt,
                const float* __restrict__ asrc1, const float* __restrict__ atgt1,
                float* __restrict__ s_src, float* __restrict__ s_tgt, int M){
  const int K = KC*32;
  __shared__ short lA[64*32];     // 4 KB
  __shared__ short lB[256*32];    // 16 KB
  const int tid  = threadIdx.x;
  const int lane = tid & 63;
  const int wave = tid >> 6;
  const int m16  = lane & 15;
  const int q    = lane >> 4;
  const int swz  = (m16 >> 1) & 3;
  const int r0   = blockIdx.x * 64;
  const bool first = (blockIdx.y == 0);
  const short* __restrict__ Bt = first ? B1t : B2t;

  int arow = r0 + (tid >> 2); if (arow >= M) arow = M - 1;
  const int akq = (tid & 3) ^ ((tid >> 3) & 3);
  int bn[4], bkq[4];
  #pragma unroll
  for (int j = 0; j < 4; j++){
    int sj = j*256 + tid;
    bn[j]  = sj >> 2;
    bkq[j] = (sj & 3) ^ ((sj >> 3) & 3);
  }

  f32x4 acc[4][4];
  #pragma unroll
  for (int mi = 0; mi < 4; mi++)
    #pragma unroll
    for (int ni = 0; ni < 4; ni++) acc[mi][ni] = {0.f,0.f,0.f,0.f};

  s16x8 ra = loadA<AF32>(Ab, (size_t)arow*K + akq*8);
  s16x8 rb[4];
  #pragma unroll
  for (int j = 0; j < 4; j++)
    rb[j] = *(const s16x8*)(Bt + (size_t)bn[j]*K + bkq[j]*8);

  for (int c = 0; c < KC; c++){
    __syncthreads();
    *(s16x8*)(lA + tid*8) = ra;
    #pragma unroll
    for (int j = 0; j < 4; j++)
      *(s16x8*)(lB + (j*256 + tid)*8) = rb[j];
    __syncthreads();

    if (c + 1 < KC){
      int k0 = (c+1)*32;
      ra = loadA<AF32>(Ab, (size_t)arow*K + k0 + akq*8);
      #pragma unroll
      for (int j = 0; j < 4; j++)
        rb[j] = *(const s16x8*)(Bt + (size_t)bn[j]*K + k0 + bkq[j]*8);
    }

    s16x8 Af[4], Bf[4];
    #pragma unroll
    for (int mi = 0; mi < 4; mi++){
      int slot = (mi*16 + m16)*4 + (q ^ swz);
      Af[mi] = *(const s16x8*)(lA + slot*8);
    }
    #pragma unroll
    for (int ni = 0; ni < 4; ni++){
      int n = wave*64 + ni*16 + m16;
      int slot = n*4 + (q ^ swz);
      Bf[ni] = *(const s16x8*)(lB + slot*8);
    }
    #pragma unroll
    for (int mi = 0; mi < 4; mi++)
      #pragma unroll
      for (int ni = 0; ni < 4; ni++)
        acc[mi][ni] = __builtin_amdgcn_mfma_f32_16x16x32_f16(
            *(h16x8*)&Bf[ni], *(h16x8*)&Af[mi], acc[mi][ni], 0, 0, 0);
  }

  // ---- skip write (fp16), y=1 ----
  if (!first && C2b){
    #pragma unroll
    for (int mi = 0; mi < 4; mi++){
      int row = r0 + mi*16 + m16;
      if (row < M){
        #pragma unroll
        for (int ni = 0; ni < 4; ni++){
          size_t o = (size_t)row*256 + wave*64 + ni*16 + q*4;
          short4 u; u.x = f2h(acc[mi][ni][0]); u.y = f2h(acc[mi][ni][1]);
          u.z = f2h(acc[mi][ni][2]); u.w = f2h(acc[mi][ni][3]);
          *(short4*)(C2b + o) = u;
        }
      }
    }
  }

  // ---- fused NH=16 svec (y=0) ----
  if (first && asrc){
    #pragma unroll
    for (int mi = 0; mi < 4; mi++){
      int row = r0 + mi*16 + m16;
      bool ok = (row < M);
      #pragma unroll
      for (int ni = 0; ni < 4; ni++){
        int hh = wave*4 + ni;
        const float* as = asrc + hh*16 + q*4;
        const float* at = atgt + hh*16 + q*4;
        float pss = acc[mi][ni][0]*as[0] + acc[mi][ni][1]*as[1]
                  + acc[mi][ni][2]*as[2] + acc[mi][ni][3]*as[3];
        float pst = acc[mi][ni][0]*at[0] + acc[mi][ni][1]*at[1]
                  + acc[mi][ni][2]*at[2] + acc[mi][ni][3]*at[3];
        pss += __shfl_xor(pss, 16); pss += __shfl_xor(pss, 32);
        pst += __shfl_xor(pst, 16); pst += __shfl_xor(pst, 32);
        if (ok && q == 0){
          s_src[row*16 + hh] = pss;
          s_tgt[row*16 + hh] = pst;
        }
      }
    }
  }

  // ---- fused NH=1 svec (layer 2): full 256-col dot per row, cross-wave LDS reduce ----
  if (first && asrc1){
    float pss[4], pst[4];
    #pragma unroll
    for (int mi = 0; mi < 4; mi++){
      float ss = 0.f, st = 0.f;
      #pragma unroll
      for (int ni = 0; ni < 4; ni++){
        const float* as = asrc1 + wave*64 + ni*16 + q*4;
        const float* at = atgt1 + wave*64 + ni*16 + q*4;
        #pragma unroll
        for (int k = 0; k < 4; k++){
          ss += acc[mi][ni][k]*as[k];
          st += acc[mi][ni][k]*at[k];
        }
      }
      ss += __shfl_xor(ss, 16); ss += __shfl_xor(ss, 32);
      st += __shfl_xor(st, 16); st += __shfl_xor(st, 32);
      pss[mi] = ss; pst[mi] = st;
    }
    __syncthreads();                       // main-loop lB reads done
    float* sred = (float*)lB;              // [2][4 waves][64 rows] = 2 KB
    if (q == 0){
      #pragma unroll
      for (int mi = 0; mi < 4; mi++){
        int r = mi*16 + m16;
        sred[wave*64 + r]       = pss[mi];
        sred[256 + wave*64 + r] = pst[mi];
      }
    }
    __syncthreads();
    if (tid < 64){
      int row = r0 + tid;
      if (row < M){
        float ss = sred[tid] + sred[64+tid] + sred[128+tid] + sred[192+tid];
        float st = sred[256+tid] + sred[320+tid] + sred[384+tid] + sred[448+tid];
        s_src[row] = ss;
        s_tgt[row] = st;
      }
    }
  }

  // ---- per-row-scaled int8 encode (message proj, all layers) ----
  if (first && C8){
    // row max |x| over 256 cols: reduce over k,ni (in-lane), q (shfl), waves (LDS)
    float am[4];
    #pragma unroll
    for (int mi = 0; mi < 4; mi++){
      float a = 0.f;
      #pragma unroll
      for (int ni = 0; ni < 4; ni++)
        #pragma unroll
        for (int k = 0; k < 4; k++)
          a = fmaxf(a, fabsf(acc[mi][ni][k]));
      a = fmaxf(a, __shfl_xor(a, 16));
      a = fmaxf(a, __shfl_xor(a, 32));
      am[mi] = a;
    }
    __syncthreads();                      // all waves done with prior LDS use
    float* rmax = (float*)lA;             // [wave][64 rows] = 1 KB, reuse lA
    if (q == 0){
      #pragma unroll
      for (int mi = 0; mi < 4; mi++) rmax[wave*64 + mi*16 + m16] = am[mi];
    }
    __syncthreads();
    #pragma unroll
    for (int mi = 0; mi < 4; mi++){
      int r = mi*16 + m16;
      int row = r0 + r;
      bool ok = (row < M);
      float s = fmaxf(fmaxf(rmax[r], rmax[64+r]), fmaxf(rmax[128+r], rmax[192+r]));
      float scl = s * (1.f/127.f);
      float inv = (s > 0.f) ? (127.f/s) : 0.f;
      if (ok && wave == 0 && q == 0) pscale[row] = scl;
      if (ok){
        #pragma unroll
        for (int ni = 0; ni < 4; ni++){
          int v0 = __float2int_rn(acc[mi][ni][0]*inv) + 128;
          int v1 = __float2int_rn(acc[mi][ni][1]*inv) + 128;
          int v2 = __float2int_rn(acc[mi][ni][2]*inv) + 128;
          int v3 = __float2int_rn(acc[mi][ni][3]*inv) + 128;
          unsigned pk = (unsigned)(v0 & 255) | ((unsigned)(v1 & 255) << 8)
                      | ((unsigned)(v2 & 255) << 16) | ((unsigned)(v3 & 255) << 24);
          *(unsigned*)(C8 + (size_t)row*256 + wave*64 + ni*16 + q*4) = pk;
        }
      }
    }
  }
}

// ---------------- single-pass fused attention, NH=16 (int8 proj gather) ----------------
template<int LN>
__global__ __launch_bounds__(256)
void k_attn16(const int* __restrict__ row_start, const int2* __restrict__ es,
              const float* __restrict__ s_src, const float* __restrict__ s_tgt,
              const float* __restrict__ cvec,
              const unsigned char* __restrict__ proj8, const float* __restrict__ pscale,
              const short* __restrict__ skipb,
              const float* __restrict__ bias,
              const float* __restrict__ ln_g, const float* __restrict__ ln_b,
              short* __restrict__ houtb, int N){
  __shared__ __align__(16) float wbuf[4][16][20];   // [wave][head][edge(16)+pad]
  __shared__ __align__(16) int   svbuf[4][16];
  __shared__ __align__(16) float scbuf[4][16];
  const int lane = threadIdx.x & 63;
  const int wave = threadIdx.x >> 6;
  const int node = blockIdx.x*4 + wave;
  if (node >= N) return;
  const int beg = row_start[node], end = row_start[node+1];

  const int h2 = lane >> 2;      // head owning this lane's 4 features (aggregation)
  const int j4 = lane & 15;      // edge slot (score phase)
  const int g  = lane >> 4;      // head-quad (score phase)

  const f32x4 stg = *(const f32x4*)(s_tgt + (size_t)node*16 + g*4);
  const f32x4 cg  = *(const f32x4*)(cvec + g*4);

  float d = 0.f, dws = 0.f;
  float acc0 = 0.f, acc1 = 0.f, acc2 = 0.f, acc3 = 0.f;

  for (int s0 = beg; s0 < end; s0 += 16){
    int cnt = end - s0; if (cnt > 16) cnt = 16;
    // ---- Phase A: scores for 16 edges x 16 heads ----
    int i  = s0 + j4;
    bool valid = (i < end);
    int ic = valid ? i : (end - 1);
    int2 e2 = es[ic];
    int sv = e2.x;
    float tp = __int_as_float(e2.y);
    f32x4 rv = *(const f32x4*)(s_src + (size_t)sv*16 + g*4);
    if (g == 0){ svbuf[wave][j4] = sv; scbuf[wave][j4] = pscale[sv]; }
    #pragma unroll
    for (int k = 0; k < 4; k++){
      float e = rv[k] + stg[k] + tp*cg[k];
      e = (e > 0.f) ? e : 0.2f*e;
      wbuf[wave][g*4 + k][j4] = valid ? __expf(e) : 0.f;
    }
    // ---- Phase B: int8 gather + f32 accumulate (pads carry w=0, sv clamped) ----
    const unsigned* __restrict__ pp = (const unsigned*)proj8 + lane;
    for (int j = 0; j < cnt; j += 4){
      f32x4 w4  = *(const f32x4*)&wbuf[wave][h2][j];
      f32x4 sc4 = *(const f32x4*)&scbuf[wave][j];
      i32x4 sv4 = *(const i32x4*)&svbuf[wave][j];
      unsigned q0 = pp[(size_t)sv4.x*64];
      unsigned q1 = pp[(size_t)sv4.y*64];
      unsigned q2 = pp[(size_t)sv4.z*64];
      unsigned q3 = pp[(size_t)sv4.w*64];
      float ws0 = w4.x*sc4.x, ws1 = w4.y*sc4.y, ws2 = w4.z*sc4.z, ws3 = w4.w*sc4.w;
      d   += (w4.x + w4.y) + (w4.z + w4.w);
      dws += (ws0 + ws1) + (ws2 + ws3);
      acc0 += ws0*(float)(q0 & 255) + ws1*(float)(q1 & 255)
            + ws2*(float)(q2 & 255) + ws3*(float)(q3 & 255);
      acc1 += ws0*(float)((q0 >> 8) & 255) + ws1*(float)((q1 >> 8) & 255)
            + ws2*(float)((q2 >> 8) & 255) + ws3*(float)((q3 >> 8) & 255);
      acc2 += ws0*(float)((q0 >> 16) & 255) + ws1*(float)((q1 >> 16) & 255)
            + ws2*(float)((q2 >> 16) & 255) + ws3*(float)((q3 >> 16) & 255);
      acc3 += ws0*(float)(q0 >> 24) + ws1*(float)(q1 >> 24)
            + ws2*(float)(q2 >> 24) + ws3*(float)(q3 >> 24);
    }
  }
  float inv = 1.f / (d + 1e-16f);
  float c128 = 128.f * dws;

  short4 sk = ((const short4*)(skipb + (size_t)node*256))[lane];
  float acc[4];
  acc[0] = (acc0 - c128)*inv + h2f(sk.x); acc[1] = (acc1 - c128)*inv + h2f(sk.y);
  acc[2] = (acc2 - c128)*inv + h2f(sk.z); acc[3] = (acc3 - c128)*inv + h2f(sk.w);

  #pragma unroll
  for (int j = 0; j < 4; j++){
    float v = acc[j] + bias[lane*4 + j];
    acc[j] = (v > 0.f) ? v : (__expf(v) - 1.f);
  }
  if (LN){
    float s  = acc[0] + acc[1] + acc[2] + acc[3];
    float s2 = acc[0]*acc[0] + acc[1]*acc[1] + acc[2]*acc[2] + acc[3]*acc[3];
    for (int o = 32; o > 0; o >>= 1){ s += __shfl_xor(s, o); s2 += __shfl_xor(s2, o); }
    float mu  = s * (1.f/256.f);
    float var = s2 * (1.f/256.f) - mu*mu;
    float rs  = rsqrtf(var + 1e-5f);
    #pragma unroll
    for (int j = 0; j < 4; j++)
      acc[j] = (acc[j] - mu)*rs*ln_g[lane*4 + j] + ln_b[lane*4 + j];
  }
  short4 ub; ub.x = f2h(acc[0]); ub.y = f2h(acc[1]);
  ub.z = f2h(acc[2]); ub.w = f2h(acc[3]);
  ((short4*)(houtb + (size_t)node*256))[lane] = ub;
}

// NH=1 variant (layer 2): int8 message gather; scores from fused GEMM-epilogue svec.
// Identity skip, LN, fp16 out.
__global__ __launch_bounds__(256)
void k_attn1(const int* __restrict__ row_start, const int2* __restrict__ es,
             const float* __restrict__ s_src, const float* __restrict__ s_tgt,
             const float* __restrict__ cvec,
             const unsigned char* __restrict__ proj8, const float* __restrict__ pscale,
             const short* __restrict__ skipb,
             const float* __restrict__ bias,
             const float* __restrict__ ln_g, const float* __restrict__ ln_b,
             short* __restrict__ houtb, int N){
  __shared__ __align__(16) float wb1[4][64];
  __shared__ __align__(16) int   sb1[4][64];
  __shared__ __align__(16) float scb1[4][64];
  const int lane = threadIdx.x & 63;
  const int wave = threadIdx.x >> 6;
  const int node = blockIdx.x*4 + wave;
  if (node >= N) return;
  const int beg = row_start[node], end = row_start[node+1];

  const float c0 = cvec[0];
  const float st = s_tgt[node];
  float d = 0.f, dws = 0.f;
  float acc0 = 0.f, acc1 = 0.f, acc2 = 0.f, acc3 = 0.f;

  for (int s0 = beg; s0 < end; s0 += 64){
    int cnt = end - s0; if (cnt > 64) cnt = 64;
    // ---- Phase A: one edge per lane ----
    int i  = s0 + lane;
    bool valid = (i < end);
    int ic = valid ? i : (end - 1);
    int2 e2 = es[ic];
    int sv = e2.x;
    float e = s_src[sv] + st + __int_as_float(e2.y)*c0;
    e = (e > 0.f) ? e : 0.2f*e;
    float w = valid ? __expf(e) : 0.f;
    wb1[wave][lane] = w;
    sb1[wave][lane] = sv;
    scb1[wave][lane] = pscale[sv];
    // ---- Phase B: int8 gather + f32 accumulate (pads carry w=0, sv clamped) ----
    const unsigned* __restrict__ pp = (const unsigned*)proj8 + lane;
    for (int j = 0; j < cnt; j += 4){
      f32x4 w4  = *(const f32x4*)&wb1[wave][j];
      f32x4 sc4 = *(const f32x4*)&scb1[wave][j];
      i32x4 sv4 = *(const i32x4*)&sb1[wave][j];
      unsigned q0 = pp[(size_t)sv4.x*64];
      unsigned q1 = pp[(size_t)sv4.y*64];
      unsigned q2 = pp[(size_t)sv4.z*64];
      unsigned q3 = pp[(size_t)sv4.w*64];
      float ws0 = w4.x*sc4.x, ws1 = w4.y*sc4.y, ws2 = w4.z*sc4.z, ws3 = w4.w*sc4.w;
      d   += (w4.x + w4.y) + (w4.z + w4.w);
      dws += (ws0 + ws1) + (ws2 + ws3);
      acc0 += ws0*(float)(q0 & 255) + ws1*(float)(q1 & 255)
            + ws2*(float)(q2 & 255) + ws3*(float)(q3 & 255);
      acc1 += ws0*(float)((q0 >> 8) & 255) + ws1*(float)((q1 >> 8) & 255)
            + ws2*(float)((q2 >> 8) & 255) + ws3*(float)((q3 >> 8) & 255);
      acc2 += ws0*(float)((q0 >> 16) & 255) + ws1*(float)((q1 >> 16) & 255)
            + ws2*(float)((q2 >> 16) & 255) + ws3*(float)((q3 >> 16) & 255);
      acc3 += ws0*(float)(q0 >> 24) + ws1*(float)(q1 >> 24)
            + ws2*(float)(q2 >> 24) + ws3*(float)(q3 >> 24);
    }
  }
  float inv = 1.f / (d + 1e-16f);
  float c128 = 128.f * dws;

  short4 sk = ((const short4*)(skipb + (size_t)node*256))[lane];
  float acc[4];
  acc[0] = (acc0 - c128)*inv + h2f(sk.x); acc[1] = (acc1 - c128)*inv + h2f(sk.y);
  acc[2] = (acc2 - c128)*inv + h2f(sk.z); acc[3] = (acc3 - c128)*inv + h2f(sk.w);

  #pragma unroll
  for (int j = 0; j < 4; j++){
    float v = acc[j] + bias[lane*4 + j];
    acc[j] = (v > 0.f) ? v : (__expf(v) - 1.f);
  }
  float s  = acc[0] + acc[1] + acc[2] + acc[3];
  float s2 = acc[0]*acc[0] + acc[1]*acc[1] + acc[2]*acc[2] + acc[3]*acc[3];
  for (int o = 32; o > 0; o >>= 1){ s += __shfl_xor(s, o); s2 += __shfl_xor(s2, o); }
  float mu  = s * (1.f/256.f);
  float var = s2 * (1.f/256.f) - mu*mu;
  float rs  = rsqrtf(var + 1e-5f);
  #pragma unroll
  for (int j = 0; j < 4; j++)
    acc[j] = (acc[j] - mu)*rs*ln_g[lane*4 + j] + ln_b[lane*4 + j];
  short4 ub; ub.x = f2h(acc[0]); ub.y = f2h(acc[1]);
  ub.z = f2h(acc[2]); ub.w = f2h(acc[3]);
  ((short4*)(houtb + (size_t)node*256))[lane] = ub;
}

// ---------------- final gather (fp16 h -> fp32 out) ----------------
__global__ void k_gather(const short* hb, const int* x, float* out, int R){
  int r = blockIdx.x, t = threadIdx.x;
  if (r >= R) return;
  out[(size_t)r*256 + t] = h2f(hb[(size_t)x[r]*256 + t]);
}

extern "C" void kernel_launch(void* const* d_in, const int* in_sizes, int n_in,
                              void* d_out, int out_size, void* d_ws, size_t ws_size,
                              hipStream_t stream){
  const int N = in_sizes[0] / 128;   // 50000
  const int E = in_sizes[1] / 2;     // 800000
  const int R = in_sizes[3];         // 8192

  const float* nf    = (const float*)d_in[0];
  const int*   ei    = (const int*)d_in[1];
  const float* eprob = (const float*)d_in[2];
  const int*   xidx  = (const int*)d_in[3];
  const float* W0     = (const float*)d_in[4];
  const float* a_src0 = (const float*)d_in[5];
  const float* a_tgt0 = (const float*)d_in[6];
  const float* Wtp0   = (const float*)d_in[7];
  const float* a_tp0  = (const float*)d_in[8];
  const float* Wskip0 = (const float*)d_in[9];
  const float* b0     = (const float*)d_in[10];
  const float* W1     = (const float*)d_in[11];
  const float* a_src1 = (const float*)d_in[12];
  const float* a_tgt1 = (const float*)d_in[13];
  const float* Wtp1   = (const float*)d_in[14];
  const float* a_tp1  = (const float*)d_in[15];
  const float* Wskip1 = (const float*)d_in[16];
  const float* b1     = (const float*)d_in[17];
  const float* ln1_g  = (const float*)d_in[18];
  const float* ln1_b  = (const float*)d_in[19];
  const float* W2     = (const float*)d_in[20];
  const float* a_src2 = (const float*)d_in[21];
  const float* a_tgt2 = (const float*)d_in[22];
  const float* Wtp2   = (const float*)d_in[23];
  const float* a_tp2  = (const float*)d_in[24];
  const float* b2     = (const float*)d_in[25];
  const float* ln2_g  = (const float*)d_in[26];
  const float* ln2_b  = (const float*)d_in[27];

  // ---- workspace layout (~80 MB) ----
  char* ws = (char*)d_ws;
  size_t off = 0;
  auto alloc = [&](size_t bytes)->char*{
    char* p = ws + off; off = (off + bytes + 255) & ~(size_t)255; return p;
  };
  unsigned char* P8 = (unsigned char*)alloc((size_t)N*256);  // proj, int8 (all layers)
  float* pscale    = (float*)alloc((size_t)N*4);       // per-row int8 scale
  short* hXb       = (short*)alloc((size_t)N*256*2);   // fp16 h: L0 out, then L1 out
  short* Skb       = (short*)alloc((size_t)N*256*2);   // skip GEMM out, then final h
  float* s_src     = (float*)alloc((size_t)N*16*4);
  float* s_tgt     = (float*)alloc((size_t)N*16*4);
  float* cvec      = (float*)alloc(256);
  int*   counts    = (int*)alloc((size_t)N*4);
  int*   row_start = (int*)alloc((size_t)(N+1)*4);
  int*   partials  = (int*)alloc(256*4);
  int*   rank      = (int*)alloc((size_t)E*4);         // per-edge rank within tgt
  int2*  es        = (int2*)alloc((size_t)E*8);        // packed (src, tp) sorted by tgt
  short* W0t       = (short*)alloc((size_t)128*256*2);
  short* Ws0t      = (short*)alloc((size_t)128*256*2);
  short* W1t       = (short*)alloc((size_t)256*256*2);
  short* Ws1t      = (short*)alloc((size_t)256*256*2);
  short* W2t       = (short*)alloc((size_t)256*256*2);
  (void)ws_size; (void)n_in; (void)out_size;

  const int* src = ei;
  const int* tgt = ei + E;

  // ---- prep: fused transposes+cvecs+counts-zero ----
  int prep_blocks = 1027 + (N + 255)/256;
  k_prep<<<prep_blocks, 256, 0, stream>>>(W0, Wskip0, W1, Wskip1, W2,
                                          W0t, Ws0t, W1t, Ws1t, W2t,
                                          Wtp0, a_tp0, Wtp1, a_tp1, Wtp2, a_tp2, cvec,
                                          counts, N);

  // ---- CSR build (atomic-free scatter via precomputed ranks) ----
  k_hist<<<(E+255)/256, 256, 0, stream>>>(tgt, counts, rank, E);
  int NB = (N + 1023) / 1024;
  k_scan1<<<NB, 1024, 0, stream>>>(counts, row_start, partials, N);
  k_scan3<<<(N+255)/256, 256, 0, stream>>>(row_start, partials, N, E);
  k_scatter<<<(E+255)/256, 256, 0, stream>>>(src, tgt, eprob, row_start, rank,
                                             (long long*)es, E);

  const int gt = (N + 63) / 64;   // GEMM m-tiles
  const int at = (N + 3) / 4;     // attn blocks (4 waves each)

  // ---- Layer 0: GAT(128 -> 16x16 concat), skip = nf @ Wskip0, ELU, no LN ----
  // A operand is raw fp32 node features (converted in-register).
  k_gemm_lds<4,1><<<dim3(gt,2), 256, 0, stream>>>(nf, W0t, Ws0t, Skb, P8, pscale,
                                                  a_src0, a_tgt0, nullptr, nullptr,
                                                  s_src, s_tgt, N);
  k_attn16<0><<<at, 256, 0, stream>>>(row_start, es, s_src, s_tgt, cvec + 0,
                                      P8, pscale, Skb, b0, nullptr, nullptr, hXb, N);

  // ---- Layer 1: GAT(256 -> 16x16 concat), skip = h @ Wskip1, ELU, LN ----
  k_gemm_lds<8,0><<<dim3(gt,2), 256, 0, stream>>>(hXb, W1t, Ws1t, Skb, P8, pscale,
                                                  a_src1, a_tgt1, nullptr, nullptr,
                                                  s_src, s_tgt, N);
  k_attn16<1><<<at, 256, 0, stream>>>(row_start, es, s_src, s_tgt, cvec + 16,
                                      P8, pscale, Skb, b1, ln1_g, ln1_b, hXb, N);

  // ---- Layer 2: GAT(256 -> 1x256, avg = identity), identity skip, ELU, LN ----
  // GEMM emits int8 P8 + pscale and fused NH=1 svec (s_src/s_tgt from exact f32).
  k_gemm_lds<8,0><<<dim3(gt,1), 256, 0, stream>>>(hXb, W2t, nullptr, nullptr, P8, pscale,
                                                  nullptr, nullptr, a_src2, a_tgt2,
                                                  s_src, s_tgt, N);
  k_attn1<<<at, 256, 0, stream>>>(row_start, es, s_src, s_tgt, cvec + 32,
                                  P8, pscale, hXb, b2, ln2_g, ln2_b, Skb, N);

  // ---- gather rows into output (fp32) ----
  k_gather<<<R, 256, 0, stream>>>(Skb, xidx, (float*)d_out, R);
}

// Round 14
// 438.028 us; speedup vs baseline: 1.0353x; 1.0054x over previous
//
#include <hip/hip_runtime.h>
#include <hip/hip_fp16.h>
#include <math.h>

typedef __attribute__((ext_vector_type(8))) short    s16x8;   // 8 fp16 (4 VGPRs)
typedef __attribute__((ext_vector_type(8))) _Float16 h16x8;   // MFMA f16 operand
typedef __attribute__((ext_vector_type(4))) float    f32x4;   // MFMA accumulator
typedef __attribute__((ext_vector_type(4))) int      i32x4;

__device__ __forceinline__ short f2h(float x){ return __half_as_short(__float2half(x)); }
__device__ __forceinline__ float h2f(short s){ return __half2float(__short_as_half(s)); }

// ---------------- fused prep: 5 weight transposes + 3 cvec reductions + counts zero ----
__global__ void k_prep(const float* W0, const float* Ws0, const float* W1,
                       const float* Ws1, const float* W2,
                       short* W0t, short* Ws0t, short* W1t, short* Ws1t, short* W2t,
                       const float* Wtp0, const float* a_tp0,
                       const float* Wtp1, const float* a_tp1,
                       const float* Wtp2, const float* a_tp2, float* cvec,
                       int* counts, int N){
  __shared__ float buf[256];
  int b = blockIdx.x;
  if (b < 1024){
    int idx = b*256 + threadIdx.x;           // 0..262143
    const float* W; short* Wt; int K; int base;
    if (idx < 32768)      { W=W0;  Wt=W0t;  K=128; base=0; }
    else if (idx < 65536) { W=Ws0; Wt=Ws0t; K=128; base=32768; }
    else if (idx < 131072){ W=W1;  Wt=W1t;  K=256; base=65536; }
    else if (idx < 196608){ W=Ws1; Wt=Ws1t; K=256; base=131072; }
    else                  { W=W2;  Wt=W2t;  K=256; base=196608; }
    int i = idx - base;
    int n = i / K, k = i - n*K;
    Wt[i] = f2h(W[(size_t)k*256 + n]);
  } else if (b < 1027){
    int layer = b - 1024;
    const float* Wtp = layer==0 ? Wtp0 : (layer==1 ? Wtp1 : Wtp2);
    const float* atp = layer==0 ? a_tp0 : (layer==1 ? a_tp1 : a_tp2);
    float* c = cvec + (layer==0 ? 0 : (layer==1 ? 16 : 32));
    int NH = (layer==2) ? 1 : 16;
    int t = threadIdx.x;
    buf[t] = Wtp[t] * atp[t];
    __syncthreads();
    int F = 256 / NH;
    if (t < NH){
      float s = 0.f;
      for (int f = 0; f < F; f++) s += buf[t*F + f];
      c[t] = s;
    }
  } else {
    int i = (b - 1027)*256 + threadIdx.x;
    if (i < N) counts[i] = 0;
  }
}

// ---------------- CSR build (sort edges by target) ----------------
__global__ void k_hist(const int* tgt, int* counts, int* rank, int E){
  int i = blockIdx.x*blockDim.x + threadIdx.x;
  if (i < E) rank[i] = atomicAdd(&counts[tgt[i]], 1);
}
__global__ void k_scan1(const int* counts, int* row_excl, int* partials, int N){
  __shared__ int buf[1024];
  int t = threadIdx.x; int i = blockIdx.x*1024 + t;
  int v = (i < N) ? counts[i] : 0;
  buf[t] = v; __syncthreads();
  for (int o = 1; o < 1024; o <<= 1){
    int x = (t >= o) ? buf[t-o] : 0;
    __syncthreads();
    buf[t] += x;
    __syncthreads();
  }
  if (i < N) row_excl[i] = buf[t] - v;
  if (t == 1023) partials[blockIdx.x] = buf[1023];
}
__global__ void k_scan3(int* row_start, const int* partials, int N, int E){
  __shared__ int base;
  int b = blockIdx.x;
  int pb = (b*256) >> 10;
  if (threadIdx.x == 0){
    int s = 0;
    for (int k = 0; k < pb; k++) s += partials[k];
    base = s;
  }
  __syncthreads();
  int i = b*256 + threadIdx.x;
  if (i < N) row_start[i] += base;
  if (i == 0) row_start[N] = E;
}
// atomic-free scatter: p = row_start[tgt] + rank; nontemporal 8B store
__global__ void k_scatter(const int* src, const int* tgt, const float* eprob,
                          const int* row_start, const int* rank,
                          long long* es, int E){
  int i = blockIdx.x*blockDim.x + threadIdx.x;
  if (i >= E) return;
  int p = row_start[tgt[i]] + rank[i];
  unsigned long long v = ((unsigned long long)(unsigned)__float_as_int(eprob[i]) << 32)
                       | (unsigned)src[i];
  __builtin_nontemporal_store((long long)v, es + p);
}

// ---------------- LDS-staged MFMA GEMM (fp16/fp32 in, fp16/int8 out) ----------------
template<int AF32>
__device__ __forceinline__ s16x8 loadA(const void* Ab, size_t off){
  if constexpr (AF32){
    const float* p = (const float*)Ab + off;
    float4 a0 = *(const float4*)p;
    float4 a1 = *(const float4*)(p + 4);
    s16x8 r;
    r[0]=f2h(a0.x); r[1]=f2h(a0.y); r[2]=f2h(a0.z); r[3]=f2h(a0.w);
    r[4]=f2h(a1.x); r[5]=f2h(a1.y); r[6]=f2h(a1.z); r[7]=f2h(a1.w);
    return r;
  } else {
    return *(const s16x8*)((const short*)Ab + off);
  }
}

template<int KC, int AF32>   // K/32 chunks: 4 (K=128) or 8 (K=256)
__global__ __launch_bounds__(256)
void k_gemm_lds(const void* __restrict__ Ab,
                const short* __restrict__ B1t, const short* __restrict__ B2t,
                short* __restrict__ C2b,
                unsigned char* __restrict__ C8, float* __restrict__ pscale,
                const float* __restrict__ asrc, const float* __restrict__ atgt,
                const float* __restrict__ asrc1, const float* __restrict__ atgt1,
                float* __restrict__ s_src, float* __restrict__ s_tgt, int M){
  const int K = KC*32;
  __shared__ short lA[64*32];     // 4 KB
  __shared__ short lB[256*32];    // 16 KB
  const int tid  = threadIdx.x;
  const int lane = tid & 63;
  const int wave = tid >> 6;
  const int m16  = lane & 15;
  const int q    = lane >> 4;
  const int swz  = (m16 >> 1) & 3;
  const int r0   = blockIdx.x * 64;
  const bool first = (blockIdx.y == 0);
  const short* __restrict__ Bt = first ? B1t : B2t;

  int arow = r0 + (tid >> 2); if (arow >= M) arow = M - 1;
  const int akq = (tid & 3) ^ ((tid >> 3) & 3);
  int bn[4], bkq[4];
  #pragma unroll
  for (int j = 0; j < 4; j++){
    int sj = j*256 + tid;
    bn[j]  = sj >> 2;
    bkq[j] = (sj & 3) ^ ((sj >> 3) & 3);
  }

  f32x4 acc[4][4];
  #pragma unroll
  for (int mi = 0; mi < 4; mi++)
    #pragma unroll
    for (int ni = 0; ni < 4; ni++) acc[mi][ni] = {0.f,0.f,0.f,0.f};

  s16x8 ra = loadA<AF32>(Ab, (size_t)arow*K + akq*8);
  s16x8 rb[4];
  #pragma unroll
  for (int j = 0; j < 4; j++)
    rb[j] = *(const s16x8*)(Bt + (size_t)bn[j]*K + bkq[j]*8);

  for (int c = 0; c < KC; c++){
    __syncthreads();
    *(s16x8*)(lA + tid*8) = ra;
    #pragma unroll
    for (int j = 0; j < 4; j++)
      *(s16x8*)(lB + (j*256 + tid)*8) = rb[j];
    __syncthreads();

    if (c + 1 < KC){
      int k0 = (c+1)*32;
      ra = loadA<AF32>(Ab, (size_t)arow*K + k0 + akq*8);
      #pragma unroll
      for (int j = 0; j < 4; j++)
        rb[j] = *(const s16x8*)(Bt + (size_t)bn[j]*K + k0 + bkq[j]*8);
    }

    s16x8 Af[4], Bf[4];
    #pragma unroll
    for (int mi = 0; mi < 4; mi++){
      int slot = (mi*16 + m16)*4 + (q ^ swz);
      Af[mi] = *(const s16x8*)(lA + slot*8);
    }
    #pragma unroll
    for (int ni = 0; ni < 4; ni++){
      int n = wave*64 + ni*16 + m16;
      int slot = n*4 + (q ^ swz);
      Bf[ni] = *(const s16x8*)(lB + slot*8);
    }
    #pragma unroll
    for (int mi = 0; mi < 4; mi++)
      #pragma unroll
      for (int ni = 0; ni < 4; ni++)
        acc[mi][ni] = __builtin_amdgcn_mfma_f32_16x16x32_f16(
            *(h16x8*)&Bf[ni], *(h16x8*)&Af[mi], acc[mi][ni], 0, 0, 0);
  }

  // ---- skip write (fp16), y=1 ----
  if (!first && C2b){
    #pragma unroll
    for (int mi = 0; mi < 4; mi++){
      int row = r0 + mi*16 + m16;
      if (row < M){
        #pragma unroll
        for (int ni = 0; ni < 4; ni++){
          size_t o = (size_t)row*256 + wave*64 + ni*16 + q*4;
          short4 u; u.x = f2h(acc[mi][ni][0]); u.y = f2h(acc[mi][ni][1]);
          u.z = f2h(acc[mi][ni][2]); u.w = f2h(acc[mi][ni][3]);
          *(short4*)(C2b + o) = u;
        }
      }
    }
  }

  // ---- fused NH=16 svec (y=0) ----
  if (first && asrc){
    #pragma unroll
    for (int mi = 0; mi < 4; mi++){
      int row = r0 + mi*16 + m16;
      bool ok = (row < M);
      #pragma unroll
      for (int ni = 0; ni < 4; ni++){
        int hh = wave*4 + ni;
        const float* as = asrc + hh*16 + q*4;
        const float* at = atgt + hh*16 + q*4;
        float pss = acc[mi][ni][0]*as[0] + acc[mi][ni][1]*as[1]
                  + acc[mi][ni][2]*as[2] + acc[mi][ni][3]*as[3];
        float pst = acc[mi][ni][0]*at[0] + acc[mi][ni][1]*at[1]
                  + acc[mi][ni][2]*at[2] + acc[mi][ni][3]*at[3];
        pss += __shfl_xor(pss, 16); pss += __shfl_xor(pss, 32);
        pst += __shfl_xor(pst, 16); pst += __shfl_xor(pst, 32);
        if (ok && q == 0){
          s_src[row*16 + hh] = pss;
          s_tgt[row*16 + hh] = pst;
        }
      }
    }
  }

  // ---- fused NH=1 svec (layer 2): full 256-col dot per row, cross-wave LDS reduce ----
  if (first && asrc1){
    float pss[4], pst[4];
    #pragma unroll
    for (int mi = 0; mi < 4; mi++){
      float ss = 0.f, st = 0.f;
      #pragma unroll
      for (int ni = 0; ni < 4; ni++){
        const float* as = asrc1 + wave*64 + ni*16 + q*4;
        const float* at = atgt1 + wave*64 + ni*16 + q*4;
        #pragma unroll
        for (int k = 0; k < 4; k++){
          ss += acc[mi][ni][k]*as[k];
          st += acc[mi][ni][k]*at[k];
        }
      }
      ss += __shfl_xor(ss, 16); ss += __shfl_xor(ss, 32);
      st += __shfl_xor(st, 16); st += __shfl_xor(st, 32);
      pss[mi] = ss; pst[mi] = st;
    }
    __syncthreads();                       // main-loop lB reads done
    float* sred = (float*)lB;              // [2][4 waves][64 rows] = 2 KB
    if (q == 0){
      #pragma unroll
      for (int mi = 0; mi < 4; mi++){
        int r = mi*16 + m16;
        sred[wave*64 + r]       = pss[mi];
        sred[256 + wave*64 + r] = pst[mi];
      }
    }
    __syncthreads();
    if (tid < 64){
      int row = r0 + tid;
      if (row < M){
        float ss = sred[tid] + sred[64+tid] + sred[128+tid] + sred[192+tid];
        float st = sred[256+tid] + sred[320+tid] + sred[384+tid] + sred[448+tid];
        s_src[row] = ss;
        s_tgt[row] = st;
      }
    }
  }

  // ---- per-row-scaled int8 encode (message proj, all layers) ----
  if (first && C8){
    float am[4];
    #pragma unroll
    for (int mi = 0; mi < 4; mi++){
      float a = 0.f;
      #pragma unroll
      for (int ni = 0; ni < 4; ni++)
        #pragma unroll
        for (int k = 0; k < 4; k++)
          a = fmaxf(a, fabsf(acc[mi][ni][k]));
      a = fmaxf(a, __shfl_xor(a, 16));
      a = fmaxf(a, __shfl_xor(a, 32));
      am[mi] = a;
    }
    __syncthreads();                      // all waves done with prior LDS use
    float* rmax = (float*)lA;             // [wave][64 rows] = 1 KB, reuse lA
    if (q == 0){
      #pragma unroll
      for (int mi = 0; mi < 4; mi++) rmax[wave*64 + mi*16 + m16] = am[mi];
    }
    __syncthreads();
    #pragma unroll
    for (int mi = 0; mi < 4; mi++){
      int r = mi*16 + m16;
      int row = r0 + r;
      bool ok = (row < M);
      float s = fmaxf(fmaxf(rmax[r], rmax[64+r]), fmaxf(rmax[128+r], rmax[192+r]));
      float scl = s * (1.f/127.f);
      float inv = (s > 0.f) ? (127.f/s) : 0.f;
      if (ok && wave == 0 && q == 0) pscale[row] = scl;
      if (ok){
        #pragma unroll
        for (int ni = 0; ni < 4; ni++){
          int v0 = __float2int_rn(acc[mi][ni][0]*inv) + 128;
          int v1 = __float2int_rn(acc[mi][ni][1]*inv) + 128;
          int v2 = __float2int_rn(acc[mi][ni][2]*inv) + 128;
          int v3 = __float2int_rn(acc[mi][ni][3]*inv) + 128;
          unsigned pk = (unsigned)(v0 & 255) | ((unsigned)(v1 & 255) << 8)
                      | ((unsigned)(v2 & 255) << 16) | ((unsigned)(v3 & 255) << 24);
          *(unsigned*)(C8 + (size_t)row*256 + wave*64 + ni*16 + q*4) = pk;
        }
      }
    }
  }
}

// ---------------- single-pass fused attention, NH=16 (int8 proj gather) ----------------
// 32-bit byte-offset addressing for all gathers (sv < 2^23: offsets fit 32 bits) —
// lets the compiler emit saddr-form global loads (SGPR base + 32-bit voffset),
// cutting 64-bit address arithmetic from the per-edge critical VALU path.
template<int LN>
__global__ __launch_bounds__(256)
void k_attn16(const int* __restrict__ row_start, const int2* __restrict__ es,
              const float* __restrict__ s_src, const float* __restrict__ s_tgt,
              const float* __restrict__ cvec,
              const unsigned char* __restrict__ proj8, const float* __restrict__ pscale,
              const short* __restrict__ skipb,
              const float* __restrict__ bias,
              const float* __restrict__ ln_g, const float* __restrict__ ln_b,
              short* __restrict__ houtb, int N){
  __shared__ __align__(16) float wbuf[4][16][20];   // [wave][head][edge(16)+pad]
  __shared__ __align__(16) int   svbuf[4][16];
  __shared__ __align__(16) float scbuf[4][16];
  const int lane = threadIdx.x & 63;
  const int wave = threadIdx.x >> 6;
  const int node = blockIdx.x*4 + wave;
  if (node >= N) return;
  const int beg = row_start[node], end = row_start[node+1];

  const int h2 = lane >> 2;      // head owning this lane's 4 features (aggregation)
  const int j4 = lane & 15;      // edge slot (score phase)
  const int g  = lane >> 4;      // head-quad (score phase)
  const unsigned lane4 = (unsigned)lane << 2;   // byte offset of this lane's word

  const char* __restrict__ esb = (const char*)es;
  const char* __restrict__ ssb = (const char*)s_src;
  const char* __restrict__ scb = (const char*)pscale;
  const char* __restrict__ ppb = (const char*)proj8;

  const f32x4 stg = *(const f32x4*)(s_tgt + (size_t)node*16 + g*4);
  const f32x4 cg  = *(const f32x4*)(cvec + g*4);

  float d = 0.f, dws = 0.f;
  float acc0 = 0.f, acc1 = 0.f, acc2 = 0.f, acc3 = 0.f;

  for (int s0 = beg; s0 < end; s0 += 16){
    int cnt = end - s0; if (cnt > 16) cnt = 16;
    // ---- Phase A: scores for 16 edges x 16 heads ----
    int i  = s0 + j4;
    bool valid = (i < end);
    unsigned ic = (unsigned)(valid ? i : (end - 1));
    int2 e2 = *(const int2*)(esb + ((size_t)ic << 3));
    int sv = e2.x;
    float tp = __int_as_float(e2.y);
    f32x4 rv = *(const f32x4*)(ssb + (((unsigned)sv << 6) + ((unsigned)g << 4)));
    if (g == 0){
      svbuf[wave][j4] = sv;
      scbuf[wave][j4] = *(const float*)(scb + ((unsigned)sv << 2));
    }
    #pragma unroll
    for (int k = 0; k < 4; k++){
      float e = rv[k] + stg[k] + tp*cg[k];
      e = (e > 0.f) ? e : 0.2f*e;
      wbuf[wave][g*4 + k][j4] = valid ? __expf(e) : 0.f;
    }
    // ---- Phase B: int8 gather + f32 accumulate (pads carry w=0, sv clamped) ----
    for (int j = 0; j < cnt; j += 4){
      f32x4 w4  = *(const f32x4*)&wbuf[wave][h2][j];
      f32x4 sc4 = *(const f32x4*)&scbuf[wave][j];
      i32x4 sv4 = *(const i32x4*)&svbuf[wave][j];
      unsigned q0 = *(const unsigned*)(ppb + (((unsigned)sv4.x << 8) + lane4));
      unsigned q1 = *(const unsigned*)(ppb + (((unsigned)sv4.y << 8) + lane4));
      unsigned q2 = *(const unsigned*)(ppb + (((unsigned)sv4.z << 8) + lane4));
      unsigned q3 = *(const unsigned*)(ppb + (((unsigned)sv4.w << 8) + lane4));
      float ws0 = w4.x*sc4.x, ws1 = w4.y*sc4.y, ws2 = w4.z*sc4.z, ws3 = w4.w*sc4.w;
      d   += (w4.x + w4.y) + (w4.z + w4.w);
      dws += (ws0 + ws1) + (ws2 + ws3);
      acc0 += ws0*(float)(q0 & 255) + ws1*(float)(q1 & 255)
            + ws2*(float)(q2 & 255) + ws3*(float)(q3 & 255);
      acc1 += ws0*(float)((q0 >> 8) & 255) + ws1*(float)((q1 >> 8) & 255)
            + ws2*(float)((q2 >> 8) & 255) + ws3*(float)((q3 >> 8) & 255);
      acc2 += ws0*(float)((q0 >> 16) & 255) + ws1*(float)((q1 >> 16) & 255)
            + ws2*(float)((q2 >> 16) & 255) + ws3*(float)((q3 >> 16) & 255);
      acc3 += ws0*(float)(q0 >> 24) + ws1*(float)(q1 >> 24)
            + ws2*(float)(q2 >> 24) + ws3*(float)(q3 >> 24);
    }
  }
  float inv = 1.f / (d + 1e-16f);
  float c128 = 128.f * dws;

  short4 sk = ((const short4*)(skipb + (size_t)node*256))[lane];
  float acc[4];
  acc[0] = (acc0 - c128)*inv + h2f(sk.x); acc[1] = (acc1 - c128)*inv + h2f(sk.y);
  acc[2] = (acc2 - c128)*inv + h2f(sk.z); acc[3] = (acc3 - c128)*inv + h2f(sk.w);

  #pragma unroll
  for (int j = 0; j < 4; j++){
    float v = acc[j] + bias[lane*4 + j];
    acc[j] = (v > 0.f) ? v : (__expf(v) - 1.f);
  }
  if (LN){
    float s  = acc[0] + acc[1] + acc[2] + acc[3];
    float s2 = acc[0]*acc[0] + acc[1]*acc[1] + acc[2]*acc[2] + acc[3]*acc[3];
    for (int o = 32; o > 0; o >>= 1){ s += __shfl_xor(s, o); s2 += __shfl_xor(s2, o); }
    float mu  = s * (1.f/256.f);
    float var = s2 * (1.f/256.f) - mu*mu;
    float rs  = rsqrtf(var + 1e-5f);
    #pragma unroll
    for (int j = 0; j < 4; j++)
      acc[j] = (acc[j] - mu)*rs*ln_g[lane*4 + j] + ln_b[lane*4 + j];
  }
  short4 ub; ub.x = f2h(acc[0]); ub.y = f2h(acc[1]);
  ub.z = f2h(acc[2]); ub.w = f2h(acc[3]);
  ((short4*)(houtb + (size_t)node*256))[lane] = ub;
}

// NH=1 variant (layer 2): int8 message gather; scores from fused GEMM-epilogue svec.
// Same 32-bit byte-offset addressing. Identity skip, LN, fp16 out.
__global__ __launch_bounds__(256)
void k_attn1(const int* __restrict__ row_start, const int2* __restrict__ es,
             const float* __restrict__ s_src, const float* __restrict__ s_tgt,
             const float* __restrict__ cvec,
             const unsigned char* __restrict__ proj8, const float* __restrict__ pscale,
             const short* __restrict__ skipb,
             const float* __restrict__ bias,
             const float* __restrict__ ln_g, const float* __restrict__ ln_b,
             short* __restrict__ houtb, int N){
  __shared__ __align__(16) float wb1[4][64];
  __shared__ __align__(16) int   sb1[4][64];
  __shared__ __align__(16) float scb1[4][64];
  const int lane = threadIdx.x & 63;
  const int wave = threadIdx.x >> 6;
  const int node = blockIdx.x*4 + wave;
  if (node >= N) return;
  const int beg = row_start[node], end = row_start[node+1];
  const unsigned lane4 = (unsigned)lane << 2;

  const char* __restrict__ esb = (const char*)es;
  const char* __restrict__ ssb = (const char*)s_src;
  const char* __restrict__ scb = (const char*)pscale;
  const char* __restrict__ ppb = (const char*)proj8;

  const float c0 = cvec[0];
  const float st = s_tgt[node];
  float d = 0.f, dws = 0.f;
  float acc0 = 0.f, acc1 = 0.f, acc2 = 0.f, acc3 = 0.f;

  for (int s0 = beg; s0 < end; s0 += 64){
    int cnt = end - s0; if (cnt > 64) cnt = 64;
    // ---- Phase A: one edge per lane ----
    int i  = s0 + lane;
    bool valid = (i < end);
    unsigned ic = (unsigned)(valid ? i : (end - 1));
    int2 e2 = *(const int2*)(esb + ((size_t)ic << 3));
    int sv = e2.x;
    float e = *(const float*)(ssb + ((unsigned)sv << 2)) + st + __int_as_float(e2.y)*c0;
    e = (e > 0.f) ? e : 0.2f*e;
    float w = valid ? __expf(e) : 0.f;
    wb1[wave][lane] = w;
    sb1[wave][lane] = sv;
    scb1[wave][lane] = *(const float*)(scb + ((unsigned)sv << 2));
    // ---- Phase B: int8 gather + f32 accumulate (pads carry w=0, sv clamped) ----
    for (int j = 0; j < cnt; j += 4){
      f32x4 w4  = *(const f32x4*)&wb1[wave][j];
      f32x4 sc4 = *(const f32x4*)&scb1[wave][j];
      i32x4 sv4 = *(const i32x4*)&sb1[wave][j];
      unsigned q0 = *(const unsigned*)(ppb + (((unsigned)sv4.x << 8) + lane4));
      unsigned q1 = *(const unsigned*)(ppb + (((unsigned)sv4.y << 8) + lane4));
      unsigned q2 = *(const unsigned*)(ppb + (((unsigned)sv4.z << 8) + lane4));
      unsigned q3 = *(const unsigned*)(ppb + (((unsigned)sv4.w << 8) + lane4));
      float ws0 = w4.x*sc4.x, ws1 = w4.y*sc4.y, ws2 = w4.z*sc4.z, ws3 = w4.w*sc4.w;
      d   += (w4.x + w4.y) + (w4.z + w4.w);
      dws += (ws0 + ws1) + (ws2 + ws3);
      acc0 += ws0*(float)(q0 & 255) + ws1*(float)(q1 & 255)
            + ws2*(float)(q2 & 255) + ws3*(float)(q3 & 255);
      acc1 += ws0*(float)((q0 >> 8) & 255) + ws1*(float)((q1 >> 8) & 255)
            + ws2*(float)((q2 >> 8) & 255) + ws3*(float)((q3 >> 8) & 255);
      acc2 += ws0*(float)((q0 >> 16) & 255) + ws1*(float)((q1 >> 16) & 255)
            + ws2*(float)((q2 >> 16) & 255) + ws3*(float)((q3 >> 16) & 255);
      acc3 += ws0*(float)(q0 >> 24) + ws1*(float)(q1 >> 24)
            + ws2*(float)(q2 >> 24) + ws3*(float)(q3 >> 24);
    }
  }
  float inv = 1.f / (d + 1e-16f);
  float c128 = 128.f * dws;

  short4 sk = ((const short4*)(skipb + (size_t)node*256))[lane];
  float acc[4];
  acc[0] = (acc0 - c128)*inv + h2f(sk.x); acc[1] = (acc1 - c128)*inv + h2f(sk.y);
  acc[2] = (acc2 - c128)*inv + h2f(sk.z); acc[3] = (acc3 - c128)*inv + h2f(sk.w);

  #pragma unroll
  for (int j = 0; j < 4; j++){
    float v = acc[j] + bias[lane*4 + j];
    acc[j] = (v > 0.f) ? v : (__expf(v) - 1.f);
  }
  float s  = acc[0] + acc[1] + acc[2] + acc[3];
  float s2 = acc[0]*acc[0] + acc[1]*acc[1] + acc[2]*acc[2] + acc[3]*acc[3];
  for (int o = 32; o > 0; o >>= 1){ s += __shfl_xor(s, o); s2 += __shfl_xor(s2, o); }
  float mu  = s * (1.f/256.f);
  float var = s2 * (1.f/256.f) - mu*mu;
  float rs  = rsqrtf(var + 1e-5f);
  #pragma unroll
  for (int j = 0; j < 4; j++)
    acc[j] = (acc[j] - mu)*rs*ln_g[lane*4 + j] + ln_b[lane*4 + j];
  short4 ub; ub.x = f2h(acc[0]); ub.y = f2h(acc[1]);
  ub.z = f2h(acc[2]); ub.w = f2h(acc[3]);
  ((short4*)(houtb + (size_t)node*256))[lane] = ub;
}

// ---------------- final gather (fp16 h -> fp32 out) ----------------
__global__ void k_gather(const short* hb, const int* x, float* out, int R){
  int r = blockIdx.x, t = threadIdx.x;
  if (r >= R) return;
  out[(size_t)r*256 + t] = h2f(hb[(size_t)x[r]*256 + t]);
}

extern "C" void kernel_launch(void* const* d_in, const int* in_sizes, int n_in,
                              void* d_out, int out_size, void* d_ws, size_t ws_size,
                              hipStream_t stream){
  const int N = in_sizes[0] / 128;   // 50000
  const int E = in_sizes[1] / 2;     // 800000
  const int R = in_sizes[3];         // 8192

  const float* nf    = (const float*)d_in[0];
  const int*   ei    = (const int*)d_in[1];
  const float* eprob = (const float*)d_in[2];
  const int*   xidx  = (const int*)d_in[3];
  const float* W0     = (const float*)d_in[4];
  const float* a_src0 = (const float*)d_in[5];
  const float* a_tgt0 = (const float*)d_in[6];
  const float* Wtp0   = (const float*)d_in[7];
  const float* a_tp0  = (const float*)d_in[8];
  const float* Wskip0 = (const float*)d_in[9];
  const float* b0     = (const float*)d_in[10];
  const float* W1     = (const float*)d_in[11];
  const float* a_src1 = (const float*)d_in[12];
  const float* a_tgt1 = (const float*)d_in[13];
  const float* Wtp1   = (const float*)d_in[14];
  const float* a_tp1  = (const float*)d_in[15];
  const float* Wskip1 = (const float*)d_in[16];
  const float* b1     = (const float*)d_in[17];
  const float* ln1_g  = (const float*)d_in[18];
  const float* ln1_b  = (const float*)d_in[19];
  const float* W2     = (const float*)d_in[20];
  const float* a_src2 = (const float*)d_in[21];
  const float* a_tgt2 = (const float*)d_in[22];
  const float* Wtp2   = (const float*)d_in[23];
  const float* a_tp2  = (const float*)d_in[24];
  const float* b2     = (const float*)d_in[25];
  const float* ln2_g  = (const float*)d_in[26];
  const float* ln2_b  = (const float*)d_in[27];

  // ---- workspace layout (~80 MB) ----
  char* ws = (char*)d_ws;
  size_t off = 0;
  auto alloc = [&](size_t bytes)->char*{
    char* p = ws + off; off = (off + bytes + 255) & ~(size_t)255; return p;
  };
  unsigned char* P8 = (unsigned char*)alloc((size_t)N*256);  // proj, int8 (all layers)
  float* pscale    = (float*)alloc((size_t)N*4);       // per-row int8 scale
  short* hXb       = (short*)alloc((size_t)N*256*2);   // fp16 h: L0 out, then L1 out
  short* Skb       = (short*)alloc((size_t)N*256*2);   // skip GEMM out, then final h
  float* s_src     = (float*)alloc((size_t)N*16*4);
  float* s_tgt     = (float*)alloc((size_t)N*16*4);
  float* cvec      = (float*)alloc(256);
  int*   counts    = (int*)alloc((size_t)N*4);
  int*   row_start = (int*)alloc((size_t)(N+1)*4);
  int*   partials  = (int*)alloc(256*4);
  int*   rank      = (int*)alloc((size_t)E*4);         // per-edge rank within tgt
  int2*  es        = (int2*)alloc((size_t)E*8);        // packed (src, tp) sorted by tgt
  short* W0t       = (short*)alloc((size_t)128*256*2);
  short* Ws0t      = (short*)alloc((size_t)128*256*2);
  short* W1t       = (short*)alloc((size_t)256*256*2);
  short* Ws1t      = (short*)alloc((size_t)256*256*2);
  short* W2t       = (short*)alloc((size_t)256*256*2);
  (void)ws_size; (void)n_in; (void)out_size;

  const int* src = ei;
  const int* tgt = ei + E;

  // ---- prep: fused transposes+cvecs+counts-zero ----
  int prep_blocks = 1027 + (N + 255)/256;
  k_prep<<<prep_blocks, 256, 0, stream>>>(W0, Wskip0, W1, Wskip1, W2,
                                          W0t, Ws0t, W1t, Ws1t, W2t,
                                          Wtp0, a_tp0, Wtp1, a_tp1, Wtp2, a_tp2, cvec,
                                          counts, N);

  // ---- CSR build (atomic-free scatter via precomputed ranks) ----
  k_hist<<<(E+255)/256, 256, 0, stream>>>(tgt, counts, rank, E);
  int NB = (N + 1023) / 1024;
  k_scan1<<<NB, 1024, 0, stream>>>(counts, row_start, partials, N);
  k_scan3<<<(N+255)/256, 256, 0, stream>>>(row_start, partials, N, E);
  k_scatter<<<(E+255)/256, 256, 0, stream>>>(src, tgt, eprob, row_start, rank,
                                             (long long*)es, E);

  const int gt = (N + 63) / 64;   // GEMM m-tiles
  const int at = (N + 3) / 4;     // attn blocks (4 waves each)

  // ---- Layer 0: GAT(128 -> 16x16 concat), skip = nf @ Wskip0, ELU, no LN ----
  k_gemm_lds<4,1><<<dim3(gt,2), 256, 0, stream>>>(nf, W0t, Ws0t, Skb, P8, pscale,
                                                  a_src0, a_tgt0, nullptr, nullptr,
                                                  s_src, s_tgt, N);
  k_attn16<0><<<at, 256, 0, stream>>>(row_start, es, s_src, s_tgt, cvec + 0,
                                      P8, pscale, Skb, b0, nullptr, nullptr, hXb, N);

  // ---- Layer 1: GAT(256 -> 16x16 concat), skip = h @ Wskip1, ELU, LN ----
  k_gemm_lds<8,0><<<dim3(gt,2), 256, 0, stream>>>(hXb, W1t, Ws1t, Skb, P8, pscale,
                                                  a_src1, a_tgt1, nullptr, nullptr,
                                                  s_src, s_tgt, N);
  k_attn16<1><<<at, 256, 0, stream>>>(row_start, es, s_src, s_tgt, cvec + 16,
                                      P8, pscale, Skb, b1, ln1_g, ln1_b, hXb, N);

  // ---- Layer 2: GAT(256 -> 1x256, avg = identity), identity skip, ELU, LN ----
  k_gemm_lds<8,0><<<dim3(gt,1), 256, 0, stream>>>(hXb, W2t, nullptr, nullptr, P8, pscale,
                                                  nullptr, nullptr, a_src2, a_tgt2,
                                                  s_src, s_tgt, N);
  k_attn1<<<at, 256, 0, stream>>>(row_start, es, s_src, s_tgt, cvec + 32,
                                  P8, pscale, hXb, b2, ln2_g, ln2_b, Skb, N);

  // ---- gather rows into output (fp32) ----
  k_gather<<<R, 256, 0, stream>>>(Skb, xidx, (float*)d_out, R);
}